// Round 1
// baseline (496.413 us; speedup 1.0000x reference)
//
#include <hip/hip_runtime.h>
#include <hip/hip_bf16.h>

#define TT 4096
#define DD 1024
#define TBB 1024
#define WBB 256

typedef __attribute__((ext_vector_type(8))) short short8;
typedef __attribute__((ext_vector_type(4))) float f32x4;

__device__ __forceinline__ unsigned short f2bf(float v) {
  __hip_bfloat16 h = __float2bfloat16(v);
  return *reinterpret_cast<unsigned short*>(&h);
}
__device__ __forceinline__ float bf2f(unsigned short u) {
  union { unsigned int i; float f; } x; x.i = ((unsigned int)u) << 16; return x.f;
}

__device__ __forceinline__ void gl_lds16(const unsigned short* g, unsigned short* l) {
  __builtin_amdgcn_global_load_lds(
      (const __attribute__((address_space(1))) void*)(unsigned long long)(g),
      (__attribute__((address_space(3))) void*)(unsigned long long)(l),
      16, 0, 0);
}

__device__ __forceinline__ float waveSum(float v) {
#pragma unroll
  for (int o = 32; o > 0; o >>= 1) v += __shfl_down(v, o, 64);
  return v;
}
__device__ __forceinline__ float waveMax(float v) {
#pragma unroll
  for (int o = 32; o > 0; o >>= 1) v = fmaxf(v, __shfl_down(v, o, 64));
  return v;
}

// Generic C = A (MxK) * B^T (B is NxK), 128x128 tile, 4 waves, mfma 16x16x32 bf16.
// EPI: 0 plain, 1 -> 1-acc, 2 -> +e0[row*1024+col] (abs-pos), 3 -> +ent/dep cols, 4 -> split hi/lo out
// SPLIT: inputs given as hi (A,B) + lo (Al,Bl), 3 mfma products (hi*hi + hi*lo + lo*hi)
template <int EPI, bool SPLIT, typename OutT>
__global__ __launch_bounds__(256) void gemm_bt(
    const unsigned short* __restrict__ A, const unsigned short* __restrict__ Al,
    const unsigned short* __restrict__ B, const unsigned short* __restrict__ Bl,
    OutT* __restrict__ C, unsigned short* __restrict__ Cl,
    int K, int lda, int ldb, int ldc,
    int zbase, int zdiv,
    long sAi, long sAj, long sBi, long sBj, long sCi, long sCj,
    long sAz, long sBz, long sCz,
    const float* __restrict__ e0, const float* __restrict__ e1,
    const float* __restrict__ e2, const float* __restrict__ e3)
{
  __shared__ __align__(16) unsigned short lA[4096];
  __shared__ __align__(16) unsigned short lB[4096];
  __shared__ __align__(16) unsigned short lAl[SPLIT ? 4096 : 64];
  __shared__ __align__(16) unsigned short lBl[SPLIT ? 4096 : 64];

  const int z = blockIdx.z, gz = zbase + z;
  const int zi = gz / zdiv, zj = gz - zi * zdiv;
  const long offA = (long)zi * sAi + (long)zj * sAj + (long)z * sAz;
  const long offB = (long)zi * sBi + (long)zj * sBj + (long)z * sBz;
  const long offC = (long)zi * sCi + (long)zj * sCj + (long)z * sCz;
  const unsigned short* Ab = A + offA;
  const unsigned short* Bb = B + offB;
  const unsigned short* Abl = SPLIT ? (Al + offA) : nullptr;
  const unsigned short* Bbl = SPLIT ? (Bl + offB) : nullptr;

  const int m0 = blockIdx.y * 128, n0 = blockIdx.x * 128;
  const int tid = threadIdx.x, wave = tid >> 6, lane = tid & 63;
  const int wm = (wave >> 1) * 64, wn = (wave & 1) * 64;
  const int srow = lane >> 2, scol = (lane & 3) * 8;
  const int lrow = lane & 15, quad = lane >> 4;

  f32x4 acc[4][4] = {};

  for (int k0 = 0; k0 < K; k0 += 32) {
#pragma unroll
    for (int t = 0; t < 2; ++t) {
      const int r = wave * 32 + t * 16 + srow;
      gl_lds16(Ab + (long)(m0 + r) * lda + (k0 + scol), &lA[wave * 1024 + t * 512]);
      gl_lds16(Bb + (long)(n0 + r) * ldb + (k0 + scol), &lB[wave * 1024 + t * 512]);
      if constexpr (SPLIT) {
        gl_lds16(Abl + (long)(m0 + r) * lda + (k0 + scol), &lAl[wave * 1024 + t * 512]);
        gl_lds16(Bbl + (long)(n0 + r) * ldb + (k0 + scol), &lBl[wave * 1024 + t * 512]);
      }
    }
    __syncthreads();

    short8 af[4], bfr[4], afl[4], bfl[4];
#pragma unroll
    for (int mi = 0; mi < 4; ++mi)
      af[mi] = *(const short8*)&lA[(wm + mi * 16 + lrow) * 32 + quad * 8];
#pragma unroll
    for (int ni = 0; ni < 4; ++ni)
      bfr[ni] = *(const short8*)&lB[(wn + ni * 16 + lrow) * 32 + quad * 8];
    if constexpr (SPLIT) {
#pragma unroll
      for (int mi = 0; mi < 4; ++mi)
        afl[mi] = *(const short8*)&lAl[(wm + mi * 16 + lrow) * 32 + quad * 8];
#pragma unroll
      for (int ni = 0; ni < 4; ++ni)
        bfl[ni] = *(const short8*)&lBl[(wn + ni * 16 + lrow) * 32 + quad * 8];
    }

#pragma unroll
    for (int mi = 0; mi < 4; ++mi)
#pragma unroll
      for (int ni = 0; ni < 4; ++ni) {
        acc[mi][ni] = __builtin_amdgcn_mfma_f32_16x16x32_bf16(af[mi], bfr[ni], acc[mi][ni], 0, 0, 0);
        if constexpr (SPLIT) {
          acc[mi][ni] = __builtin_amdgcn_mfma_f32_16x16x32_bf16(af[mi], bfl[ni], acc[mi][ni], 0, 0, 0);
          acc[mi][ni] = __builtin_amdgcn_mfma_f32_16x16x32_bf16(afl[mi], bfr[ni], acc[mi][ni], 0, 0, 0);
        }
      }
    __syncthreads();
  }

  OutT* Cb = C + offC;
  unsigned short* Clb = (EPI == 4) ? (Cl + offC) : nullptr;
#pragma unroll
  for (int mi = 0; mi < 4; ++mi)
#pragma unroll
    for (int ni = 0; ni < 4; ++ni)
#pragma unroll
      for (int r = 0; r < 4; ++r) {
        const int row = m0 + wm + mi * 16 + quad * 4 + r;
        const int col = n0 + wn + ni * 16 + lrow;
        float v = acc[mi][ni][r];
        if constexpr (EPI == 1) v = 1.0f - v;
        if constexpr (EPI == 2) v += e0[(long)row * 1024 + col];
        if constexpr (EPI == 3)
          v += e0[(long)gz * 1024 + row] * e2[col] + e1[(long)gz * 1024 + row] * e3[col];
        const long ci = (long)row * ldc + col;
        if constexpr (EPI == 4) {
          const unsigned short hi = f2bf(v);
          Cb[ci] = (OutT)hi;
          Clb[ci] = f2bf(v - bf2f(hi));
        } else if constexpr (sizeof(OutT) == 2) {
          Cb[ci] = (OutT)f2bf(v);
        } else {
          Cb[ci] = v;
        }
      }
}

__global__ __launch_bounds__(256) void prepx_kernel(
    const float* __restrict__ x, unsigned short* __restrict__ xhi,
    unsigned short* __restrict__ xlo, unsigned short* __restrict__ xu)
{
  const int t = blockIdx.x, tid = threadIdx.x;
  const float* row = x + (long)t * DD;
  float v[4]; float ss = 0.f;
#pragma unroll
  for (int p = 0; p < 4; ++p) { v[p] = row[tid + p * 256]; ss += v[p] * v[p]; }
  ss = waveSum(ss);
  __shared__ float red[4];
  if ((tid & 63) == 0) red[tid >> 6] = ss;
  __syncthreads();
  const float tot = red[0] + red[1] + red[2] + red[3];
  const float inv = 1.f / fmaxf(sqrtf(tot), 1e-12f);
#pragma unroll
  for (int p = 0; p < 4; ++p) {
    const long i = (long)t * DD + tid + p * 256;
    const unsigned short h = f2bf(v[p]);
    xhi[i] = h;
    xlo[i] = f2bf(v[p] - bf2f(h));
    xu[i] = f2bf(v[p] * inv);
  }
}

__global__ __launch_bounds__(256) void castw_kernel(
    const float* __restrict__ Wq, const float* __restrict__ Wk, const float* __restrict__ Wv,
    unsigned short* __restrict__ hi, unsigned short* __restrict__ lo)
{
  const long idx = (long)blockIdx.x * 256 + threadIdx.x;
  const int which = (int)(idx >> 20);
  const long loc = idx & ((1L << 20) - 1);
  const float* src = (which == 0) ? Wq : ((which == 1) ? Wk : Wv);
  const float v = src[loc];
  const unsigned short h = f2bf(v);
  hi[idx] = h;
  lo[idx] = f2bf(v - bf2f(h));
}

__global__ __launch_bounds__(256) void castp_kernel(const float* __restrict__ src,
                                                    unsigned short* __restrict__ dst)
{
  const long idx = (long)blockIdx.x * 256 + threadIdx.x;
  dst[idx] = f2bf(src[idx]);
}

__global__ __launch_bounds__(256) void packw2_kernel(
    const float* __restrict__ W2, unsigned short* __restrict__ W2B,
    float* __restrict__ Ecol, float* __restrict__ Dcol)
{
  const int c = blockIdx.x, j = threadIdx.x;
  W2B[c * 256 + j] = f2bf(W2[c * 258 + j]);
  if (j == 0) {
    Ecol[c] = W2[c * 258 + 256];
    Dcol[c] = W2[c * 258 + 257];
  }
}

__global__ __launch_bounds__(256) void ap_kernel(float* __restrict__ AP)
{
  const int p = blockIdx.x, tid = threadIdx.x;
#pragma unroll
  for (int t = 0; t < 4; ++t) {
    const int col = tid + t * 256;
    const int i = col >> 1;
    const float e = (2.0f * (float)i) / 1024.0f;
    const float ang = (float)p / powf(10000.0f, e);
    AP[(long)p * 1024 + col] = (col & 1) ? cosf(ang) : sinf(ang);
  }
}

__global__ __launch_bounds__(256) void transpose_kernel(
    const unsigned short* __restrict__ V, unsigned short* __restrict__ Vt)
{
  __shared__ unsigned short tile[32][33];
  const int tx = threadIdx.x & 31, ty = threadIdx.x >> 5;
  const int c0 = blockIdx.x * 32;
  const int r0 = blockIdx.y * 32;
#pragma unroll
  for (int rr = ty; rr < 32; rr += 8)
    tile[rr][tx] = V[(long)(r0 + rr) * DD + c0 + tx];
  __syncthreads();
#pragma unroll
  for (int rr = ty; rr < 32; rr += 8)
    Vt[(long)(c0 + rr) * TT + r0 + tx] = tile[tx][rr];
}

__global__ __launch_bounds__(256) void dsum_kernel(const float* __restrict__ divb,
                                                   float* __restrict__ dsum)
{
  const int q = blockIdx.x, i = blockIdx.y, tid = threadIdx.x;
  const float* row = divb + ((long)i * TBB + q) * TBB;
  float s = row[tid] + row[tid + 256] + row[tid + 512] + row[tid + 768];
  s = waveSum(s);
  __shared__ float red[4];
  if ((tid & 63) == 0) red[tid >> 6] = s;
  __syncthreads();
  if (tid == 0) dsum[(long)i * TBB + q] = red[0] + red[1] + red[2] + red[3];
}

__global__ __launch_bounds__(256) void stats_kernel(
    const float* __restrict__ sim, const float* __restrict__ divb,
    const float* __restrict__ dsum, float* __restrict__ mrow,
    float* __restrict__ lrow, float* __restrict__ dep,
    float* __restrict__ ent, int zbase)
{
  const int q = blockIdx.x, z = blockIdx.y, gz = zbase + z, bi = gz >> 2;
  const int tid = threadIdx.x;
  const float* srow = sim + ((long)z * TBB + q) * TBB;
  const float* drow = divb + ((long)bi * TBB + q) * TBB;
  float s[4], d[4];
#pragma unroll
  for (int p = 0; p < 4; ++p) { s[p] = srow[tid + p * 256]; d[p] = drow[tid + p * 256]; }
  float m = fmaxf(fmaxf(s[0], s[1]), fmaxf(s[2], s[3]));
  m = waveMax(m);
  __shared__ float red[4];
  if ((tid & 63) == 0) red[tid >> 6] = m;
  __syncthreads();
  m = fmaxf(fmaxf(red[0], red[1]), fmaxf(red[2], red[3]));
  float l = 0.f, ss = 0.f, dn = 0.f;
#pragma unroll
  for (int p = 0; p < 4; ++p) {
    const float e = expf(s[p] - m);
    l += e; ss += e * s[p]; dn += e * d[p];
  }
  l = waveSum(l); ss = waveSum(ss); dn = waveSum(dn);
  __shared__ float r2[12];
  if ((tid & 63) == 0) { const int w = tid >> 6; r2[w] = l; r2[4 + w] = ss; r2[8 + w] = dn; }
  __syncthreads();
  if (tid == 0) {
    const float L = r2[0] + r2[1] + r2[2] + r2[3];
    const float SS = r2[4] + r2[5] + r2[6] + r2[7];
    const float DN = r2[8] + r2[9] + r2[10] + r2[11];
    const long o = (long)gz * TBB + q;
    mrow[o] = m;
    lrow[o] = L;
    dep[o] = (DN / L) / dsum[(long)bi * TBB + q];
    ent[o] = (m + logf(L) - SS / L) * 0.14426950408889634f;  // 1/ln(1024)
  }
}

__global__ __launch_bounds__(256) void entnorm_kernel(float* __restrict__ ent)
{
  const int gz = blockIdx.x, tid = threadIdx.x;
  float s = 0.f;
#pragma unroll
  for (int p = 0; p < 4; ++p) s += fabsf(ent[(long)gz * TBB + tid + p * 256]);
  s = waveSum(s);
  __shared__ float red[4];
  if ((tid & 63) == 0) red[tid >> 6] = s;
  __syncthreads();
  const float scale = 1.f / fmaxf(red[0] + red[1] + red[2] + red[3], 1e-12f);
#pragma unroll
  for (int p = 0; p < 4; ++p) ent[(long)gz * TBB + tid + p * 256] *= scale;
}

__global__ __launch_bounds__(256) void w_kernel(
    const float* __restrict__ sim, const float* __restrict__ mrow,
    const float* __restrict__ lrow, const float* __restrict__ dep,
    unsigned short* __restrict__ wb, int zbase)
{
  const long idx4 = ((long)blockIdx.x * 256 + threadIdx.x) * 4;
  const int z = (int)(idx4 >> 20);
  const int q = (int)((idx4 >> 10) & 1023);
  const int k = (int)(idx4 & 1023);
  const int gz = zbase + z;
  const float4 sv = *(const float4*)(sim + idx4);
  const long o = (long)gz * TBB + q;
  const float m = mrow[o], li = 1.f / lrow[o];
  const float* dp = dep + (long)gz * TBB + k;
  ushort4 w;
  w.x = f2bf(expf(sv.x - m) * li * (1.f + dp[0]));
  w.y = f2bf(expf(sv.y - m) * li * (1.f + dp[1]));
  w.z = f2bf(expf(sv.z - m) * li * (1.f + dp[2]));
  w.w = f2bf(expf(sv.w - m) * li * (1.f + dp[3]));
  *(ushort4*)(wb + idx4) = w;
}

extern "C" void kernel_launch(void* const* d_in, const int* in_sizes, int n_in,
                              void* d_out, int out_size, void* d_ws, size_t ws_size,
                              hipStream_t stream)
{
  const float* x  = (const float*)d_in[0];
  const float* Wq = (const float*)d_in[1];
  const float* Wk = (const float*)d_in[2];
  const float* Wv = (const float*)d_in[3];
  const float* Wo = (const float*)d_in[4];
  const float* W2 = (const float*)d_in[5];

  char* ws = (char*)d_ws;
  size_t off = 0;
  auto take = [&](size_t bytes) -> void* {
    void* p = ws + off;
    off += (bytes + 255) & ~(size_t)255;
    return p;
  };
  unsigned short* QKVhi = (unsigned short*)take((size_t)3 * TT * DD * 2);
  unsigned short* QKVlo = (unsigned short*)take((size_t)3 * TT * DD * 2);
  unsigned short* xhi = (unsigned short*)take((size_t)TT * DD * 2);
  unsigned short* xlo = (unsigned short*)take((size_t)TT * DD * 2);
  unsigned short* xu  = (unsigned short*)take((size_t)TT * DD * 2);
  unsigned short* Whi = (unsigned short*)take((size_t)3 * DD * DD * 2);
  unsigned short* Wlo = (unsigned short*)take((size_t)3 * DD * DD * 2);
  unsigned short* WoB = (unsigned short*)take((size_t)DD * DD * 2);
  unsigned short* W2B = (unsigned short*)take((size_t)256 * 256 * 2);
  float* Ecol = (float*)take(256 * 4);
  float* Dcol = (float*)take(256 * 4);
  float* AP   = (float*)take((size_t)TBB * TBB * 4);
  float* divb = (float*)take((size_t)4 * TBB * TBB * 4);
  float* dsum = (float*)take((size_t)4 * TBB * 4);
  unsigned short* Vt = (unsigned short*)take((size_t)DD * TT * 2);
  float* simb = (float*)take((size_t)4 * TBB * TBB * 4);
  unsigned short* wbuf = (unsigned short*)take((size_t)4 * TBB * TBB * 2);
  float* mrow = (float*)take((size_t)16 * TBB * 4);
  float* lrow = (float*)take((size_t)16 * TBB * 4);
  float* depb = (float*)take((size_t)16 * TBB * 4);
  float* entb = (float*)take((size_t)16 * TBB * 4);
  unsigned short* ctx = (unsigned short*)take((size_t)16 * TBB * WBB * 2);
  unsigned short* Y = (unsigned short*)take((size_t)TT * DD * 2);
  (void)ws_size; (void)in_sizes; (void)n_in; (void)out_size;

  prepx_kernel<<<TT, 256, 0, stream>>>(x, xhi, xlo, xu);
  castw_kernel<<<(3 * DD * DD) / 256, 256, 0, stream>>>(Wq, Wk, Wv, Whi, Wlo);
  castp_kernel<<<(DD * DD) / 256, 256, 0, stream>>>(Wo, WoB);
  packw2_kernel<<<256, 256, 0, stream>>>(W2, W2B, Ecol, Dcol);
  ap_kernel<<<TBB, 256, 0, stream>>>(AP);

  // QKV projection, split-precision in and out: Q|K|V [4096,1024] each
  gemm_bt<4, true, unsigned short><<<dim3(DD / 128, TT / 128, 3), 256, 0, stream>>>(
      xhi, xlo, Whi, Wlo, QKVhi, QKVlo,
      DD, DD, DD, DD, 0, 1,
      0, 0, (long)DD * DD, 0, (long)TT * DD, 0,
      0, 0, 0, nullptr, nullptr, nullptr, nullptr);

  transpose_kernel<<<dim3(DD / 32, TT / 32), 256, 0, stream>>>(QKVhi + (size_t)2 * TT * DD, Vt);

  // div diagonal blocks: 1 - xu_i @ xu_i^T
  gemm_bt<1, false, float><<<dim3(8, 8, 4), 256, 0, stream>>>(
      xu, nullptr, xu, nullptr, divb, nullptr,
      DD, DD, DD, TBB, 0, 1,
      (long)TBB * DD, 0, (long)TBB * DD, 0, (long)TBB * TBB, 0,
      0, 0, 0, nullptr, nullptr, nullptr, nullptr);

  dsum_kernel<<<dim3(TBB, 4), 256, 0, stream>>>(divb, dsum);

  const unsigned short* Qhi = QKVhi;
  const unsigned short* Qlo = QKVlo;
  const unsigned short* Khi = QKVhi + (size_t)TT * DD;
  const unsigned short* Klo = QKVlo + (size_t)TT * DD;

  for (int c0 = 0; c0 < 16; c0 += 4) {
    // sim = Qb @ Kb^T + AP, split-precision
    gemm_bt<2, true, float><<<dim3(8, 8, 4), 256, 0, stream>>>(
        Qhi, Qlo, Khi, Klo, simb, nullptr,
        WBB, DD, DD, TBB, c0, 4,
        (long)TBB * DD, WBB, (long)TBB * DD, WBB, 0, 0,
        0, 0, (long)TBB * TBB, AP, nullptr, nullptr, nullptr);
    stats_kernel<<<dim3(TBB, 4), 256, 0, stream>>>(simb, divb, dsum, mrow, lrow, depb, entb, c0);
    w_kernel<<<(4 * TBB * TBB) / 1024, 256, 0, stream>>>(simb, mrow, lrow, depb, wbuf, c0);
    // ctx = w @ Vb  (B = Vt rows j*WB.., cols i*TB..)
    gemm_bt<0, false, unsigned short><<<dim3(2, 8, 4), 256, 0, stream>>>(
        wbuf, nullptr, Vt, nullptr, ctx, nullptr,
        TBB, TBB, TT, WBB, c0, 4,
        0, 0, (long)TBB, (long)WBB * TT, (long)4 * TBB * WBB, (long)TBB * WBB,
        (long)TBB * TBB, 0, 0, nullptr, nullptr, nullptr, nullptr);
  }

  entnorm_kernel<<<16, 256, 0, stream>>>(entb);

  // y = [ctx | ent | dep] @ Wout2^T, scattered back to [4096,1024]
  gemm_bt<3, false, unsigned short><<<dim3(2, 8, 16), 256, 0, stream>>>(
      ctx, nullptr, W2B, nullptr, Y, nullptr,
      WBB, WBB, WBB, DD, 0, 4,
      (long)4 * TBB * WBB, (long)TBB * WBB, 0, 0, (long)TBB * DD, (long)WBB,
      0, 0, 0, entb, depb, Ecol, Dcol);

  // out = Y @ Wout^T
  gemm_bt<0, false, float><<<dim3(8, 32, 1), 256, 0, stream>>>(
      Y, nullptr, WoB, nullptr, (float*)d_out, nullptr,
      DD, DD, DD, DD, 0, 1,
      0, 0, 0, 0, 0, 0,
      0, 0, 0, nullptr, nullptr, nullptr, nullptr);
}

// Round 2
// 312.571 us; speedup vs baseline: 1.5882x; 1.5882x over previous
//
#include <hip/hip_runtime.h>
#include <hip/hip_bf16.h>

#define TT 4096
#define DD 1024
#define TBB 1024
#define WBB 256

typedef __attribute__((ext_vector_type(8))) _Float16 half8;
typedef __attribute__((ext_vector_type(4))) float f32x4;

__device__ __forceinline__ unsigned short f2h(float v) {
  _Float16 h = (_Float16)v;
  return *reinterpret_cast<unsigned short*>(&h);
}

__device__ __forceinline__ void gl_lds16(const unsigned short* g, unsigned short* l) {
  __builtin_amdgcn_global_load_lds(
      (const __attribute__((address_space(1))) void*)(unsigned long long)(g),
      (__attribute__((address_space(3))) void*)(unsigned long long)(l),
      16, 0, 0);
}

__device__ __forceinline__ float waveSum(float v) {
#pragma unroll
  for (int o = 32; o > 0; o >>= 1) v += __shfl_down(v, o, 64);
  return v;
}
__device__ __forceinline__ float waveMax(float v) {
#pragma unroll
  for (int o = 32; o > 0; o >>= 1) v = fmaxf(v, __shfl_down(v, o, 64));
  return v;
}

// Generic C = A (MxK) * B^T (B is NxK), fp16 inputs, 128x128 tile, 4 waves.
// EPI: 0 plain, 1 -> 1-acc, 2 -> +e0[row*1024+col] (abs-pos), 3 -> +ent/dep cols
template <int EPI, typename OutT>
__global__ __launch_bounds__(256) void gemm_bt(
    const unsigned short* __restrict__ A, const unsigned short* __restrict__ B,
    OutT* __restrict__ C,
    int K, int lda, int ldb, int ldc,
    int zbase, int zdiv,
    long sAi, long sAj, long sBi, long sBj, long sCi, long sCj,
    long sAz, long sBz, long sCz,
    const float* __restrict__ e0, const float* __restrict__ e1,
    const float* __restrict__ e2, const float* __restrict__ e3)
{
  __shared__ __align__(16) unsigned short lA[4096];
  __shared__ __align__(16) unsigned short lB[4096];

  const int z = blockIdx.z, gz = zbase + z;
  const int zi = gz / zdiv, zj = gz - zi * zdiv;
  const long offA = (long)zi * sAi + (long)zj * sAj + (long)z * sAz;
  const long offB = (long)zi * sBi + (long)zj * sBj + (long)z * sBz;
  const long offC = (long)zi * sCi + (long)zj * sCj + (long)z * sCz;
  const unsigned short* Ab = A + offA;
  const unsigned short* Bb = B + offB;

  const int m0 = blockIdx.y * 128, n0 = blockIdx.x * 128;
  const int tid = threadIdx.x, wave = tid >> 6, lane = tid & 63;
  const int wm = (wave >> 1) * 64, wn = (wave & 1) * 64;
  const int srow = lane >> 2, scol = (lane & 3) * 8;
  const int lrw = lane & 15, quad = lane >> 4;

  f32x4 acc[4][4] = {};

  for (int k0 = 0; k0 < K; k0 += 32) {
#pragma unroll
    for (int t = 0; t < 2; ++t) {
      const int r = wave * 32 + t * 16 + srow;
      gl_lds16(Ab + (long)(m0 + r) * lda + (k0 + scol), &lA[wave * 1024 + t * 512]);
      gl_lds16(Bb + (long)(n0 + r) * ldb + (k0 + scol), &lB[wave * 1024 + t * 512]);
    }
    __syncthreads();

    half8 af[4], bfr[4];
#pragma unroll
    for (int mi = 0; mi < 4; ++mi)
      af[mi] = *(const half8*)&lA[(wm + mi * 16 + lrw) * 32 + quad * 8];
#pragma unroll
    for (int ni = 0; ni < 4; ++ni)
      bfr[ni] = *(const half8*)&lB[(wn + ni * 16 + lrw) * 32 + quad * 8];

#pragma unroll
    for (int mi = 0; mi < 4; ++mi)
#pragma unroll
      for (int ni = 0; ni < 4; ++ni)
        acc[mi][ni] = __builtin_amdgcn_mfma_f32_16x16x32_f16(af[mi], bfr[ni], acc[mi][ni], 0, 0, 0);
    __syncthreads();
  }

  OutT* Cb = C + offC;
#pragma unroll
  for (int mi = 0; mi < 4; ++mi)
#pragma unroll
    for (int ni = 0; ni < 4; ++ni)
#pragma unroll
      for (int r = 0; r < 4; ++r) {
        const int row = m0 + wm + mi * 16 + quad * 4 + r;
        const int col = n0 + wn + ni * 16 + lrw;
        float v = acc[mi][ni][r];
        if constexpr (EPI == 1) v = 1.0f - v;
        if constexpr (EPI == 2) v += e0[(long)row * 1024 + col];
        if constexpr (EPI == 3)
          v += e0[(long)gz * 1024 + row] * e2[col] + e1[(long)gz * 1024 + row] * e3[col];
        const long ci = (long)row * ldc + col;
        if constexpr (sizeof(OutT) == 2) {
          Cb[ci] = (OutT)f2h(v);
        } else {
          Cb[ci] = v;
        }
      }
}

// ctx = softmax-weighted PV with fused w transform:
// A[q,k] = exp(sim[q,k]-m[q]) / l[q] * (1+dep[k])  (computed during LDS staging)
// B = Vt rows [zj*256 .. +256), k-cols [zi*1024 ..)
__global__ __launch_bounds__(256) void ctx_gemm(
    const float* __restrict__ sim, const float* __restrict__ mrow,
    const float* __restrict__ lrow, const float* __restrict__ dep,
    const unsigned short* __restrict__ Vt, unsigned short* __restrict__ ctx)
{
  __shared__ __align__(16) unsigned short lA[4096];
  __shared__ __align__(16) unsigned short lB[4096];
  __shared__ float sM[128], sLi[128], sDep[1024];

  const int gz = blockIdx.z, zi = gz >> 2, zj = gz & 3;
  const int m0 = blockIdx.y * 128, n0 = blockIdx.x * 128;
  const int tid = threadIdx.x, wave = tid >> 6, lane = tid & 63;
  const int wm = (wave >> 1) * 64, wn = (wave & 1) * 64;
  const int srow = lane >> 2, scol = (lane & 3) * 8;
  const int lrw = lane & 15, quad = lane >> 4;

  if (tid < 128) {
    sM[tid] = mrow[(long)gz * 1024 + m0 + tid];
    sLi[tid] = 1.f / lrow[(long)gz * 1024 + m0 + tid];
  }
#pragma unroll
  for (int p = 0; p < 4; ++p)
    sDep[tid + p * 256] = 1.f + dep[(long)gz * 1024 + tid + p * 256];
  __syncthreads();

  const float* Ab = sim + (long)gz * TBB * TBB;
  const unsigned short* Bb = Vt + (long)(zj * 256) * TT + (long)zi * 1024;

  f32x4 acc[4][4] = {};

  for (int k0 = 0; k0 < 1024; k0 += 32) {
#pragma unroll
    for (int t = 0; t < 2; ++t) {
      const int r = wave * 32 + t * 16 + srow;
      gl_lds16(Bb + (long)(n0 + r) * TT + (k0 + scol), &lB[wave * 1024 + t * 512]);
    }
#pragma unroll
    for (int p = 0; p < 4; ++p) {
      const int idx = p * 1024 + tid * 4;
      const int row = idx >> 5, col = idx & 31;
      const float4 s = *(const float4*)(Ab + (long)(m0 + row) * 1024 + k0 + col);
      const float mm = sM[row], li = sLi[row];
      ushort4 hh;
      hh.x = f2h(expf(s.x - mm) * li * sDep[k0 + col]);
      hh.y = f2h(expf(s.y - mm) * li * sDep[k0 + col + 1]);
      hh.z = f2h(expf(s.z - mm) * li * sDep[k0 + col + 2]);
      hh.w = f2h(expf(s.w - mm) * li * sDep[k0 + col + 3]);
      *(ushort4*)&lA[row * 32 + col] = hh;
    }
    __syncthreads();

    half8 af[4], bfr[4];
#pragma unroll
    for (int mi = 0; mi < 4; ++mi)
      af[mi] = *(const half8*)&lA[(wm + mi * 16 + lrw) * 32 + quad * 8];
#pragma unroll
    for (int ni = 0; ni < 4; ++ni)
      bfr[ni] = *(const half8*)&lB[(wn + ni * 16 + lrw) * 32 + quad * 8];

#pragma unroll
    for (int mi = 0; mi < 4; ++mi)
#pragma unroll
      for (int ni = 0; ni < 4; ++ni)
        acc[mi][ni] = __builtin_amdgcn_mfma_f32_16x16x32_f16(af[mi], bfr[ni], acc[mi][ni], 0, 0, 0);
    __syncthreads();
  }

  unsigned short* Cb = ctx + (long)gz * TBB * WBB;
#pragma unroll
  for (int mi = 0; mi < 4; ++mi)
#pragma unroll
    for (int ni = 0; ni < 4; ++ni)
#pragma unroll
      for (int r = 0; r < 4; ++r) {
        const int row = m0 + wm + mi * 16 + quad * 4 + r;
        const int col = n0 + wn + ni * 16 + lrw;
        Cb[(long)row * WBB + col] = f2h(acc[mi][ni][r]);
      }
}

__global__ __launch_bounds__(256) void prepx_kernel(
    const float* __restrict__ x, unsigned short* __restrict__ xh,
    unsigned short* __restrict__ xu)
{
  const int t = blockIdx.x, tid = threadIdx.x;
  const float* row = x + (long)t * DD;
  float v[4]; float ss = 0.f;
#pragma unroll
  for (int p = 0; p < 4; ++p) { v[p] = row[tid + p * 256]; ss += v[p] * v[p]; }
  ss = waveSum(ss);
  __shared__ float red[4];
  if ((tid & 63) == 0) red[tid >> 6] = ss;
  __syncthreads();
  const float tot = red[0] + red[1] + red[2] + red[3];
  const float inv = 1.f / fmaxf(sqrtf(tot), 1e-12f);
#pragma unroll
  for (int p = 0; p < 4; ++p) {
    const long i = (long)t * DD + tid + p * 256;
    xh[i] = f2h(v[p]);
    xu[i] = f2h(v[p] * inv);
  }
}

__global__ __launch_bounds__(256) void castw_kernel(
    const float* __restrict__ Wq, const float* __restrict__ Wk, const float* __restrict__ Wv,
    unsigned short* __restrict__ o)
{
  const long idx = (long)blockIdx.x * 256 + threadIdx.x;
  const int which = (int)(idx >> 20);
  const long loc = idx & ((1L << 20) - 1);
  const float* src = (which == 0) ? Wq : ((which == 1) ? Wk : Wv);
  o[idx] = f2h(src[loc]);
}

__global__ __launch_bounds__(256) void castp_kernel(const float* __restrict__ src,
                                                    unsigned short* __restrict__ dst)
{
  const long idx = (long)blockIdx.x * 256 + threadIdx.x;
  dst[idx] = f2h(src[idx]);
}

__global__ __launch_bounds__(256) void packw2_kernel(
    const float* __restrict__ W2, unsigned short* __restrict__ W2B,
    float* __restrict__ Ecol, float* __restrict__ Dcol)
{
  const int c = blockIdx.x, j = threadIdx.x;
  W2B[c * 256 + j] = f2h(W2[c * 258 + j]);
  if (j == 0) {
    Ecol[c] = W2[c * 258 + 256];
    Dcol[c] = W2[c * 258 + 257];
  }
}

__global__ __launch_bounds__(256) void ap_kernel(float* __restrict__ AP)
{
  const int p = blockIdx.x, tid = threadIdx.x;
#pragma unroll
  for (int t = 0; t < 4; ++t) {
    const int col = tid + t * 256;
    const int i = col >> 1;
    const float e = (2.0f * (float)i) / 1024.0f;
    const float ang = (float)p / powf(10000.0f, e);
    AP[(long)p * 1024 + col] = (col & 1) ? cosf(ang) : sinf(ang);
  }
}

__global__ __launch_bounds__(256) void transpose_kernel(
    const unsigned short* __restrict__ V, unsigned short* __restrict__ Vt)
{
  __shared__ unsigned short tile[32][33];
  const int tx = threadIdx.x & 31, ty = threadIdx.x >> 5;
  const int c0 = blockIdx.x * 32;
  const int r0 = blockIdx.y * 32;
#pragma unroll
  for (int rr = ty; rr < 32; rr += 8)
    tile[rr][tx] = V[(long)(r0 + rr) * DD + c0 + tx];
  __syncthreads();
#pragma unroll
  for (int rr = ty; rr < 32; rr += 8)
    Vt[(long)(c0 + rr) * TT + r0 + tx] = tile[tx][rr];
}

__global__ __launch_bounds__(256) void stats_kernel(
    const float* __restrict__ sim, const float* __restrict__ divb,
    float* __restrict__ mrow, float* __restrict__ lrow,
    float* __restrict__ dep, float* __restrict__ ent)
{
  const int q = blockIdx.x, gz = blockIdx.y, bi = gz >> 2;
  const int tid = threadIdx.x;
  const float* srow = sim + ((long)gz * TBB + q) * TBB;
  const float* drow = divb + ((long)bi * TBB + q) * TBB;
  float s[4], d[4];
#pragma unroll
  for (int p = 0; p < 4; ++p) { s[p] = srow[tid + p * 256]; d[p] = drow[tid + p * 256]; }
  float m = fmaxf(fmaxf(s[0], s[1]), fmaxf(s[2], s[3]));
  m = waveMax(m);
  __shared__ float red[4];
  if ((tid & 63) == 0) red[tid >> 6] = m;
  __syncthreads();
  m = fmaxf(fmaxf(red[0], red[1]), fmaxf(red[2], red[3]));
  float l = 0.f, ss = 0.f, dn = 0.f, ds = 0.f;
#pragma unroll
  for (int p = 0; p < 4; ++p) {
    const float e = expf(s[p] - m);
    l += e; ss += e * s[p]; dn += e * d[p]; ds += d[p];
  }
  l = waveSum(l); ss = waveSum(ss); dn = waveSum(dn); ds = waveSum(ds);
  __shared__ float r2[16];
  if ((tid & 63) == 0) {
    const int w = tid >> 6;
    r2[w] = l; r2[4 + w] = ss; r2[8 + w] = dn; r2[12 + w] = ds;
  }
  __syncthreads();
  if (tid == 0) {
    const float L = r2[0] + r2[1] + r2[2] + r2[3];
    const float SS = r2[4] + r2[5] + r2[6] + r2[7];
    const float DN = r2[8] + r2[9] + r2[10] + r2[11];
    const float DS = r2[12] + r2[13] + r2[14] + r2[15];
    const long o = (long)gz * TBB + q;
    mrow[o] = m;
    lrow[o] = L;
    dep[o] = (DN / L) / DS;
    ent[o] = (m + logf(L) - SS / L) * 0.14426950408889634f;  // 1/ln(1024)
  }
}

__global__ __launch_bounds__(256) void entnorm_kernel(float* __restrict__ ent)
{
  const int gz = blockIdx.x, tid = threadIdx.x;
  float s = 0.f;
#pragma unroll
  for (int p = 0; p < 4; ++p) s += fabsf(ent[(long)gz * TBB + tid + p * 256]);
  s = waveSum(s);
  __shared__ float red[4];
  if ((tid & 63) == 0) red[tid >> 6] = s;
  __syncthreads();
  const float scale = 1.f / fmaxf(red[0] + red[1] + red[2] + red[3], 1e-12f);
#pragma unroll
  for (int p = 0; p < 4; ++p) ent[(long)gz * TBB + tid + p * 256] *= scale;
}

extern "C" void kernel_launch(void* const* d_in, const int* in_sizes, int n_in,
                              void* d_out, int out_size, void* d_ws, size_t ws_size,
                              hipStream_t stream)
{
  const float* x  = (const float*)d_in[0];
  const float* Wq = (const float*)d_in[1];
  const float* Wk = (const float*)d_in[2];
  const float* Wv = (const float*)d_in[3];
  const float* Wo = (const float*)d_in[4];
  const float* W2 = (const float*)d_in[5];

  char* ws = (char*)d_ws;
  size_t off = 0;
  auto take = [&](size_t bytes) -> void* {
    void* p = ws + off;
    off += (bytes + 255) & ~(size_t)255;
    return p;
  };
  unsigned short* QKV = (unsigned short*)take((size_t)3 * TT * DD * 2);
  unsigned short* xh  = (unsigned short*)take((size_t)TT * DD * 2);
  unsigned short* xu  = (unsigned short*)take((size_t)TT * DD * 2);
  unsigned short* Wh  = (unsigned short*)take((size_t)3 * DD * DD * 2);
  unsigned short* WoB = (unsigned short*)take((size_t)DD * DD * 2);
  unsigned short* W2B = (unsigned short*)take((size_t)256 * 256 * 2);
  float* Ecol = (float*)take(256 * 4);
  float* Dcol = (float*)take(256 * 4);
  float* AP   = (float*)take((size_t)TBB * TBB * 4);
  float* divb = (float*)take((size_t)4 * TBB * TBB * 4);
  unsigned short* Vt = (unsigned short*)take((size_t)DD * TT * 2);
  float* simb = (float*)take((size_t)16 * TBB * TBB * 4);
  float* mrow = (float*)take((size_t)16 * TBB * 4);
  float* lrow = (float*)take((size_t)16 * TBB * 4);
  float* depb = (float*)take((size_t)16 * TBB * 4);
  float* entb = (float*)take((size_t)16 * TBB * 4);
  unsigned short* ctx = (unsigned short*)take((size_t)16 * TBB * WBB * 2);
  unsigned short* Y = (unsigned short*)take((size_t)TT * DD * 2);
  (void)ws_size; (void)in_sizes; (void)n_in; (void)out_size;

  prepx_kernel<<<TT, 256, 0, stream>>>(x, xh, xu);
  castw_kernel<<<(3 * DD * DD) / 256, 256, 0, stream>>>(Wq, Wk, Wv, Wh);
  castp_kernel<<<(DD * DD) / 256, 256, 0, stream>>>(Wo, WoB);
  packw2_kernel<<<256, 256, 0, stream>>>(W2, W2B, Ecol, Dcol);
  ap_kernel<<<TBB, 256, 0, stream>>>(AP);

  // QKV projection: Q|K|V [4096,1024] each, fp16
  gemm_bt<0, unsigned short><<<dim3(DD / 128, TT / 128, 3), 256, 0, stream>>>(
      xh, Wh, QKV,
      DD, DD, DD, DD, 0, 1,
      0, 0, (long)DD * DD, 0, (long)TT * DD, 0,
      0, 0, 0, nullptr, nullptr, nullptr, nullptr);

  transpose_kernel<<<dim3(DD / 32, TT / 32), 256, 0, stream>>>(QKV + (size_t)2 * TT * DD, Vt);

  // div diagonal blocks: 1 - xu_i @ xu_i^T
  gemm_bt<1, float><<<dim3(8, 8, 4), 256, 0, stream>>>(
      xu, xu, divb,
      DD, DD, DD, TBB, 0, 1,
      (long)TBB * DD, 0, (long)TBB * DD, 0, (long)TBB * TBB, 0,
      0, 0, 0, nullptr, nullptr, nullptr, nullptr);

  const unsigned short* Qh = QKV;
  const unsigned short* Kh = QKV + (size_t)TT * DD;

  // sim = Qb @ Kb^T + AP, all 16 blocks
  gemm_bt<2, float><<<dim3(8, 8, 16), 256, 0, stream>>>(
      Qh, Kh, simb,
      WBB, DD, DD, TBB, 0, 4,
      (long)TBB * DD, WBB, (long)TBB * DD, WBB, 0, 0,
      0, 0, (long)TBB * TBB, AP, nullptr, nullptr, nullptr);

  stats_kernel<<<dim3(TBB, 16), 256, 0, stream>>>(simb, divb, mrow, lrow, depb, entb);
  entnorm_kernel<<<16, 256, 0, stream>>>(entb);

  // ctx = w @ Vb with fused w transform
  ctx_gemm<<<dim3(2, 8, 16), 256, 0, stream>>>(simb, mrow, lrow, depb, Vt, ctx);

  // y = [ctx | ent | dep] @ Wout2^T, scattered back to [4096,1024]
  gemm_bt<3, unsigned short><<<dim3(2, 8, 16), 256, 0, stream>>>(
      ctx, W2B, Y,
      WBB, WBB, WBB, DD, 0, 4,
      (long)4 * TBB * WBB, (long)TBB * WBB, 0, 0, (long)TBB * DD, (long)WBB,
      0, 0, 0, entb, depb, Ecol, Dcol);

  // out = Y @ Wout^T
  gemm_bt<0, float><<<dim3(8, 32, 1), 256, 0, stream>>>(
      Y, WoB, (float*)d_out,
      DD, DD, DD, DD, 0, 1,
      0, 0, 0, 0, 0, 0,
      0, 0, 0, nullptr, nullptr, nullptr, nullptr);
}

// Round 3
// 304.930 us; speedup vs baseline: 1.6280x; 1.0251x over previous
//
#include <hip/hip_runtime.h>
#include <hip/hip_bf16.h>

#define TT 4096
#define DD 1024
#define TBB 1024
#define WBB 256

typedef __attribute__((ext_vector_type(8))) _Float16 half8;
typedef __attribute__((ext_vector_type(4))) float f32x4;

__device__ __forceinline__ unsigned short f2h(float v) {
  _Float16 h = (_Float16)v;
  return *reinterpret_cast<unsigned short*>(&h);
}
__device__ __forceinline__ float h2f(unsigned short u) {
  _Float16 h = *reinterpret_cast<_Float16*>(&u);
  return (float)h;
}

__device__ __forceinline__ void gl_lds16(const unsigned short* g, unsigned short* l) {
  __builtin_amdgcn_global_load_lds(
      (const __attribute__((address_space(1))) void*)(unsigned long long)(g),
      (__attribute__((address_space(3))) void*)(unsigned long long)(l),
      16, 0, 0);
}

__device__ __forceinline__ float waveSum(float v) {
#pragma unroll
  for (int o = 32; o > 0; o >>= 1) v += __shfl_down(v, o, 64);
  return v;
}
__device__ __forceinline__ float waveMax(float v) {
#pragma unroll
  for (int o = 32; o > 0; o >>= 1) v = fmaxf(v, __shfl_down(v, o, 64));
  return v;
}

// Generic C = A (MxK) * B^T (B is NxK), fp16 inputs, 128x128 tile, 4 waves.
// EPI: 0 plain, 1 -> 1-acc, 2 -> +e0[row*1024+col] (abs-pos), 3 -> +ent/dep cols
template <int EPI, typename OutT>
__global__ __launch_bounds__(256) void gemm_bt(
    const unsigned short* __restrict__ A, const unsigned short* __restrict__ B,
    OutT* __restrict__ C,
    int K, int lda, int ldb, int ldc,
    int zbase, int zdiv,
    long sAi, long sAj, long sBi, long sBj, long sCi, long sCj,
    long sAz, long sBz, long sCz,
    const float* __restrict__ e0, const float* __restrict__ e1,
    const float* __restrict__ e2, const float* __restrict__ e3)
{
  __shared__ __align__(16) unsigned short lA[4096];
  __shared__ __align__(16) unsigned short lB[4096];

  const int z = blockIdx.z, gz = zbase + z;
  const int zi = gz / zdiv, zj = gz - zi * zdiv;
  const long offA = (long)zi * sAi + (long)zj * sAj + (long)z * sAz;
  const long offB = (long)zi * sBi + (long)zj * sBj + (long)z * sBz;
  const long offC = (long)zi * sCi + (long)zj * sCj + (long)z * sCz;
  const unsigned short* Ab = A + offA;
  const unsigned short* Bb = B + offB;

  const int m0 = blockIdx.y * 128, n0 = blockIdx.x * 128;
  const int tid = threadIdx.x, wave = tid >> 6, lane = tid & 63;
  const int wm = (wave >> 1) * 64, wn = (wave & 1) * 64;
  const int srow = lane >> 2, scol = (lane & 3) * 8;
  const int lrw = lane & 15, quad = lane >> 4;

  f32x4 acc[4][4] = {};

  for (int k0 = 0; k0 < K; k0 += 32) {
#pragma unroll
    for (int t = 0; t < 2; ++t) {
      const int r = wave * 32 + t * 16 + srow;
      gl_lds16(Ab + (long)(m0 + r) * lda + (k0 + scol), &lA[wave * 1024 + t * 512]);
      gl_lds16(Bb + (long)(n0 + r) * ldb + (k0 + scol), &lB[wave * 1024 + t * 512]);
    }
    __syncthreads();

    half8 af[4], bfr[4];
#pragma unroll
    for (int mi = 0; mi < 4; ++mi)
      af[mi] = *(const half8*)&lA[(wm + mi * 16 + lrw) * 32 + quad * 8];
#pragma unroll
    for (int ni = 0; ni < 4; ++ni)
      bfr[ni] = *(const half8*)&lB[(wn + ni * 16 + lrw) * 32 + quad * 8];

#pragma unroll
    for (int mi = 0; mi < 4; ++mi)
#pragma unroll
      for (int ni = 0; ni < 4; ++ni)
        acc[mi][ni] = __builtin_amdgcn_mfma_f32_16x16x32_f16(af[mi], bfr[ni], acc[mi][ni], 0, 0, 0);
    __syncthreads();
  }

  OutT* Cb = C + offC;
#pragma unroll
  for (int mi = 0; mi < 4; ++mi)
#pragma unroll
    for (int ni = 0; ni < 4; ++ni)
#pragma unroll
      for (int r = 0; r < 4; ++r) {
        const int row = m0 + wm + mi * 16 + quad * 4 + r;
        const int col = n0 + wn + ni * 16 + lrw;
        float v = acc[mi][ni][r];
        if constexpr (EPI == 1) v = 1.0f - v;
        if constexpr (EPI == 2) v += e0[(long)row * 1024 + col];
        if constexpr (EPI == 3)
          v += e0[(long)gz * 1024 + row] * e2[col] + e1[(long)gz * 1024 + row] * e3[col];
        const long ci = (long)row * ldc + col;
        if constexpr (sizeof(OutT) == 2) {
          Cb[ci] = (OutT)f2h(v);
        } else {
          Cb[ci] = v;
        }
      }
}

// ctx = (w_pre * (1+dep[k])) @ Vb : near-pure GEMM.
// A = w_pre fp16 [1024x1024] per gz, scaled by (1+dep[k]) during LDS staging.
// B = Vt rows [zj*256 .. +256), k-cols [zi*1024 ..) via gl_lds16.
__global__ __launch_bounds__(256) void ctx_gemm(
    const unsigned short* __restrict__ wpre, const float* __restrict__ dep,
    const unsigned short* __restrict__ Vt, unsigned short* __restrict__ ctx)
{
  __shared__ __align__(16) unsigned short lA[4096];
  __shared__ __align__(16) unsigned short lB[4096];
  __shared__ float sDep[1024];

  const int gz = blockIdx.z, zi = gz >> 2, zj = gz & 3;
  const int m0 = blockIdx.y * 128, n0 = blockIdx.x * 128;
  const int tid = threadIdx.x, wave = tid >> 6, lane = tid & 63;
  const int wm = (wave >> 1) * 64, wn = (wave & 1) * 64;
  const int srow = lane >> 2, scol = (lane & 3) * 8;
  const int lrw = lane & 15, quad = lane >> 4;

#pragma unroll
  for (int p = 0; p < 4; ++p)
    sDep[tid + p * 256] = 1.f + dep[(long)gz * 1024 + tid + p * 256];
  __syncthreads();

  const unsigned short* Ab = wpre + (long)gz * TBB * TBB;
  const unsigned short* Bb = Vt + (long)(zj * 256) * TT + (long)zi * 1024;

  f32x4 acc[4][4] = {};

  for (int k0 = 0; k0 < 1024; k0 += 32) {
#pragma unroll
    for (int t = 0; t < 2; ++t) {
      const int r = wave * 32 + t * 16 + srow;
      gl_lds16(Bb + (long)(n0 + r) * TT + (k0 + scol), &lB[wave * 1024 + t * 512]);
    }
#pragma unroll
    for (int p = 0; p < 4; ++p) {
      const int idx = p * 1024 + tid * 4;
      const int row = idx >> 5, col = idx & 31;
      const ushort4 wv = *(const ushort4*)(Ab + (long)(m0 + row) * 1024 + k0 + col);
      ushort4 hh;
      hh.x = f2h(h2f(wv.x) * sDep[k0 + col]);
      hh.y = f2h(h2f(wv.y) * sDep[k0 + col + 1]);
      hh.z = f2h(h2f(wv.z) * sDep[k0 + col + 2]);
      hh.w = f2h(h2f(wv.w) * sDep[k0 + col + 3]);
      *(ushort4*)&lA[row * 32 + col] = hh;
    }
    __syncthreads();

    half8 af[4], bfr[4];
#pragma unroll
    for (int mi = 0; mi < 4; ++mi)
      af[mi] = *(const half8*)&lA[(wm + mi * 16 + lrw) * 32 + quad * 8];
#pragma unroll
    for (int ni = 0; ni < 4; ++ni)
      bfr[ni] = *(const half8*)&lB[(wn + ni * 16 + lrw) * 32 + quad * 8];

#pragma unroll
    for (int mi = 0; mi < 4; ++mi)
#pragma unroll
      for (int ni = 0; ni < 4; ++ni)
        acc[mi][ni] = __builtin_amdgcn_mfma_f32_16x16x32_f16(af[mi], bfr[ni], acc[mi][ni], 0, 0, 0);
    __syncthreads();
  }

  unsigned short* Cb = ctx + (long)gz * TBB * WBB;
#pragma unroll
  for (int mi = 0; mi < 4; ++mi)
#pragma unroll
    for (int ni = 0; ni < 4; ++ni)
#pragma unroll
      for (int r = 0; r < 4; ++r) {
        const int row = m0 + wm + mi * 16 + quad * 4 + r;
        const int col = n0 + wn + ni * 16 + lrw;
        Cb[(long)row * WBB + col] = f2h(acc[mi][ni][r]);
      }
}

__global__ __launch_bounds__(256) void prepx_kernel(
    const float* __restrict__ x, unsigned short* __restrict__ xh,
    unsigned short* __restrict__ xu)
{
  const int t = blockIdx.x, tid = threadIdx.x;
  const float4 v = *((const float4*)(x + (long)t * DD) + tid);
  float ss = v.x * v.x + v.y * v.y + v.z * v.z + v.w * v.w;
  ss = waveSum(ss);
  __shared__ float red[4];
  if ((tid & 63) == 0) red[tid >> 6] = ss;
  __syncthreads();
  const float tot = red[0] + red[1] + red[2] + red[3];
  const float inv = 1.f / fmaxf(sqrtf(tot), 1e-12f);
  ushort4 h, u;
  h.x = f2h(v.x); h.y = f2h(v.y); h.z = f2h(v.z); h.w = f2h(v.w);
  u.x = f2h(v.x * inv); u.y = f2h(v.y * inv); u.z = f2h(v.z * inv); u.w = f2h(v.w * inv);
  *((ushort4*)(xh + (long)t * DD) + tid) = h;
  *((ushort4*)(xu + (long)t * DD) + tid) = u;
}

__global__ __launch_bounds__(256) void castw_kernel(
    const float* __restrict__ Wq, const float* __restrict__ Wk, const float* __restrict__ Wv,
    unsigned short* __restrict__ o)
{
  const long idx4 = ((long)blockIdx.x * 256 + threadIdx.x) * 4;
  const int which = (int)(idx4 >> 20);
  const long loc = idx4 & ((1L << 20) - 1);
  const float* src = (which == 0) ? Wq : ((which == 1) ? Wk : Wv);
  const float4 v = *(const float4*)(src + loc);
  ushort4 h;
  h.x = f2h(v.x); h.y = f2h(v.y); h.z = f2h(v.z); h.w = f2h(v.w);
  *(ushort4*)(o + idx4) = h;
}

__global__ __launch_bounds__(256) void castp_kernel(const float* __restrict__ src,
                                                    unsigned short* __restrict__ dst)
{
  const long idx4 = ((long)blockIdx.x * 256 + threadIdx.x) * 4;
  const float4 v = *(const float4*)(src + idx4);
  ushort4 h;
  h.x = f2h(v.x); h.y = f2h(v.y); h.z = f2h(v.z); h.w = f2h(v.w);
  *(ushort4*)(dst + idx4) = h;
}

__global__ __launch_bounds__(256) void packw2_kernel(
    const float* __restrict__ W2, unsigned short* __restrict__ W2B,
    float* __restrict__ Ecol, float* __restrict__ Dcol)
{
  const int c = blockIdx.x, j = threadIdx.x;
  W2B[c * 256 + j] = f2h(W2[c * 258 + j]);
  if (j == 0) {
    Ecol[c] = W2[c * 258 + 256];
    Dcol[c] = W2[c * 258 + 257];
  }
}

__global__ __launch_bounds__(256) void ap_kernel(float* __restrict__ AP)
{
  const int p = blockIdx.x, tid = threadIdx.x;
#pragma unroll
  for (int t = 0; t < 4; ++t) {
    const int col = tid + t * 256;
    const int i = col >> 1;
    const float e = (2.0f * (float)i) / 1024.0f;
    const float ang = (float)p / powf(10000.0f, e);
    AP[(long)p * 1024 + col] = (col & 1) ? cosf(ang) : sinf(ang);
  }
}

__global__ __launch_bounds__(256) void transpose_kernel(
    const unsigned short* __restrict__ V, unsigned short* __restrict__ Vt)
{
  __shared__ unsigned short tile[32][33];
  const int tx = threadIdx.x & 31, ty = threadIdx.x >> 5;
  const int c0 = blockIdx.x * 32;
  const int r0 = blockIdx.y * 32;
#pragma unroll
  for (int rr = ty; rr < 32; rr += 8)
    tile[rr][tx] = V[(long)(r0 + rr) * DD + c0 + tx];
  __syncthreads();
#pragma unroll
  for (int rr = ty; rr < 32; rr += 8)
    Vt[(long)(c0 + rr) * TT + r0 + tx] = tile[tx][rr];
}

// Per (gz, q-row): full softmax stats + dep + ent, AND writes w_pre = exp(s-m)/l as fp16.
__global__ __launch_bounds__(256) void stats_kernel(
    const float* __restrict__ sim, const float* __restrict__ divb,
    float* __restrict__ mrow, float* __restrict__ lrow,
    float* __restrict__ dep, float* __restrict__ ent,
    unsigned short* __restrict__ wpre)
{
  const int q = blockIdx.x, gz = blockIdx.y, bi = gz >> 2;
  const int tid = threadIdx.x;
  const float* srow = sim + ((long)gz * TBB + q) * TBB;
  const float* drow = divb + ((long)bi * TBB + q) * TBB;
  float s[4], d[4];
#pragma unroll
  for (int p = 0; p < 4; ++p) { s[p] = srow[tid + p * 256]; d[p] = drow[tid + p * 256]; }
  float m = fmaxf(fmaxf(s[0], s[1]), fmaxf(s[2], s[3]));
  m = waveMax(m);
  __shared__ float red[4];
  if ((tid & 63) == 0) red[tid >> 6] = m;
  __syncthreads();
  m = fmaxf(fmaxf(red[0], red[1]), fmaxf(red[2], red[3]));
  float e[4];
  float l = 0.f, ss = 0.f, dn = 0.f, ds = 0.f;
#pragma unroll
  for (int p = 0; p < 4; ++p) {
    e[p] = expf(s[p] - m);
    l += e[p]; ss += e[p] * s[p]; dn += e[p] * d[p]; ds += d[p];
  }
  l = waveSum(l); ss = waveSum(ss); dn = waveSum(dn); ds = waveSum(ds);
  __shared__ float r2[16];
  if ((tid & 63) == 0) {
    const int w = tid >> 6;
    r2[w] = l; r2[4 + w] = ss; r2[8 + w] = dn; r2[12 + w] = ds;
  }
  __syncthreads();
  const float L = r2[0] + r2[1] + r2[2] + r2[3];
  const float Li = 1.f / L;
  unsigned short* wrow = wpre + ((long)gz * TBB + q) * TBB;
#pragma unroll
  for (int p = 0; p < 4; ++p) wrow[tid + p * 256] = f2h(e[p] * Li);
  if (tid == 0) {
    const float SS = r2[4] + r2[5] + r2[6] + r2[7];
    const float DN = r2[8] + r2[9] + r2[10] + r2[11];
    const float DS = r2[12] + r2[13] + r2[14] + r2[15];
    const long o = (long)gz * TBB + q;
    mrow[o] = m;
    lrow[o] = L;
    dep[o] = (DN * Li) / DS;
    ent[o] = (m + logf(L) - SS * Li) * 0.14426950408889634f;  // 1/ln(1024)
  }
}

__global__ __launch_bounds__(256) void entnorm_kernel(float* __restrict__ ent)
{
  const int gz = blockIdx.x, tid = threadIdx.x;
  float s = 0.f;
#pragma unroll
  for (int p = 0; p < 4; ++p) s += fabsf(ent[(long)gz * TBB + tid + p * 256]);
  s = waveSum(s);
  __shared__ float red[4];
  if ((tid & 63) == 0) red[tid >> 6] = s;
  __syncthreads();
  const float scale = 1.f / fmaxf(red[0] + red[1] + red[2] + red[3], 1e-12f);
#pragma unroll
  for (int p = 0; p < 4; ++p) ent[(long)gz * TBB + tid + p * 256] *= scale;
}

extern "C" void kernel_launch(void* const* d_in, const int* in_sizes, int n_in,
                              void* d_out, int out_size, void* d_ws, size_t ws_size,
                              hipStream_t stream)
{
  const float* x  = (const float*)d_in[0];
  const float* Wq = (const float*)d_in[1];
  const float* Wk = (const float*)d_in[2];
  const float* Wv = (const float*)d_in[3];
  const float* Wo = (const float*)d_in[4];
  const float* W2 = (const float*)d_in[5];

  char* ws = (char*)d_ws;
  size_t off = 0;
  auto take = [&](size_t bytes) -> void* {
    void* p = ws + off;
    off += (bytes + 255) & ~(size_t)255;
    return p;
  };
  unsigned short* QKV = (unsigned short*)take((size_t)3 * TT * DD * 2);
  unsigned short* xh  = (unsigned short*)take((size_t)TT * DD * 2);
  unsigned short* xu  = (unsigned short*)take((size_t)TT * DD * 2);
  unsigned short* Wh  = (unsigned short*)take((size_t)3 * DD * DD * 2);
  unsigned short* WoB = (unsigned short*)take((size_t)DD * DD * 2);
  unsigned short* W2B = (unsigned short*)take((size_t)256 * 256 * 2);
  float* Ecol = (float*)take(256 * 4);
  float* Dcol = (float*)take(256 * 4);
  float* AP   = (float*)take((size_t)TBB * TBB * 4);
  float* divb = (float*)take((size_t)4 * TBB * TBB * 4);
  unsigned short* Vt = (unsigned short*)take((size_t)DD * TT * 2);
  float* simb = (float*)take((size_t)16 * TBB * TBB * 4);
  unsigned short* wpre = (unsigned short*)take((size_t)16 * TBB * TBB * 2);
  float* mrow = (float*)take((size_t)16 * TBB * 4);
  float* lrow = (float*)take((size_t)16 * TBB * 4);
  float* depb = (float*)take((size_t)16 * TBB * 4);
  float* entb = (float*)take((size_t)16 * TBB * 4);
  unsigned short* ctx = (unsigned short*)take((size_t)16 * TBB * WBB * 2);
  unsigned short* Y = (unsigned short*)take((size_t)TT * DD * 2);
  (void)ws_size; (void)in_sizes; (void)n_in; (void)out_size;

  prepx_kernel<<<TT, 256, 0, stream>>>(x, xh, xu);
  castw_kernel<<<(3 * DD * DD) / 1024, 256, 0, stream>>>(Wq, Wk, Wv, Wh);
  castp_kernel<<<(DD * DD) / 1024, 256, 0, stream>>>(Wo, WoB);
  packw2_kernel<<<256, 256, 0, stream>>>(W2, W2B, Ecol, Dcol);
  ap_kernel<<<TBB, 256, 0, stream>>>(AP);

  // QKV projection: Q|K|V [4096,1024] each, fp16
  gemm_bt<0, unsigned short><<<dim3(DD / 128, TT / 128, 3), 256, 0, stream>>>(
      xh, Wh, QKV,
      DD, DD, DD, DD, 0, 1,
      0, 0, (long)DD * DD, 0, (long)TT * DD, 0,
      0, 0, 0, nullptr, nullptr, nullptr, nullptr);

  transpose_kernel<<<dim3(DD / 32, TT / 32), 256, 0, stream>>>(QKV + (size_t)2 * TT * DD, Vt);

  // div diagonal blocks: 1 - xu_i @ xu_i^T
  gemm_bt<1, float><<<dim3(8, 8, 4), 256, 0, stream>>>(
      xu, xu, divb,
      DD, DD, DD, TBB, 0, 1,
      (long)TBB * DD, 0, (long)TBB * DD, 0, (long)TBB * TBB, 0,
      0, 0, 0, nullptr, nullptr, nullptr, nullptr);

  const unsigned short* Qh = QKV;
  const unsigned short* Kh = QKV + (size_t)TT * DD;

  // sim = Qb @ Kb^T + AP, all 16 blocks
  gemm_bt<2, float><<<dim3(8, 8, 16), 256, 0, stream>>>(
      Qh, Kh, simb,
      WBB, DD, DD, TBB, 0, 4,
      (long)TBB * DD, WBB, (long)TBB * DD, WBB, 0, 0,
      0, 0, (long)TBB * TBB, AP, nullptr, nullptr, nullptr);

  stats_kernel<<<dim3(TBB, 16), 256, 0, stream>>>(simb, divb, mrow, lrow, depb, entb, wpre);
  entnorm_kernel<<<16, 256, 0, stream>>>(entb);

  // ctx = (w_pre * (1+dep[k])) @ Vb
  ctx_gemm<<<dim3(2, 8, 16), 256, 0, stream>>>(wpre, depb, Vt, ctx);

  // y = [ctx | ent | dep] @ Wout2^T, scattered back to [4096,1024]
  gemm_bt<3, unsigned short><<<dim3(2, 8, 16), 256, 0, stream>>>(
      ctx, W2B, Y,
      WBB, WBB, WBB, DD, 0, 4,
      (long)4 * TBB * WBB, (long)TBB * WBB, 0, 0, (long)TBB * DD, (long)WBB,
      0, 0, 0, entb, depb, Ecol, Dcol);

  // out = Y @ Wout^T
  gemm_bt<0, float><<<dim3(8, 32, 1), 256, 0, stream>>>(
      Y, WoB, (float*)d_out,
      DD, DD, DD, DD, 0, 1,
      0, 0, 0, 0, 0, 0,
      0, 0, 0, nullptr, nullptr, nullptr, nullptr);
}

// Round 4
// 292.567 us; speedup vs baseline: 1.6967x; 1.0423x over previous
//
#include <hip/hip_runtime.h>
#include <hip/hip_bf16.h>

#define TT 4096
#define DD 1024
#define TBB 1024
#define WBB 256

typedef __attribute__((ext_vector_type(8))) _Float16 half8;
typedef __attribute__((ext_vector_type(4))) _Float16 half4;
typedef __attribute__((ext_vector_type(4))) float f32x4;
typedef __attribute__((ext_vector_type(16))) float f32x16;

__device__ __forceinline__ unsigned short f2h(float v) {
  _Float16 h = (_Float16)v;
  return *reinterpret_cast<unsigned short*>(&h);
}
__device__ __forceinline__ float h2f(unsigned short u) {
  _Float16 h = *reinterpret_cast<_Float16*>(&u);
  return (float)h;
}

__device__ __forceinline__ void gl_lds16(const unsigned short* g, unsigned short* l) {
  __builtin_amdgcn_global_load_lds(
      (const __attribute__((address_space(1))) void*)(unsigned long long)(g),
      (__attribute__((address_space(3))) void*)(unsigned long long)(l),
      16, 0, 0);
}

__device__ __forceinline__ float waveSum(float v) {
#pragma unroll
  for (int o = 32; o > 0; o >>= 1) v += __shfl_down(v, o, 64);
  return v;
}
__device__ __forceinline__ float waveMax(float v) {
#pragma unroll
  for (int o = 32; o > 0; o >>= 1) v = fmaxf(v, __shfl_down(v, o, 64));
  return v;
}

// Generic C = A (MxK) * B^T (B is NxK), fp16, 128x128 tile, 4 waves,
// BK=64 (two 32-col half-buffers per barrier pair), mfma 32x32x16 f16.
// EPI: 0 plain, 1 -> 1-acc, 2 -> +e0[row*1024+col] (abs-pos), 3 -> +ent/dep cols
template <int EPI, typename OutT>
__global__ __launch_bounds__(256) void gemm_bt(
    const unsigned short* __restrict__ A, const unsigned short* __restrict__ B,
    OutT* __restrict__ C,
    int K, int lda, int ldb, int ldc,
    int zbase, int zdiv,
    long sAi, long sAj, long sBi, long sBj, long sCi, long sCj,
    long sAz, long sBz, long sCz,
    const float* __restrict__ e0, const float* __restrict__ e1,
    const float* __restrict__ e2, const float* __restrict__ e3)
{
  __shared__ __align__(16) unsigned short lA[2][4096];
  __shared__ __align__(16) unsigned short lB[2][4096];

  const int z = blockIdx.z, gz = zbase + z;
  const int zi = gz / zdiv, zj = gz - zi * zdiv;
  const unsigned short* Ab = A + (long)zi * sAi + (long)zj * sAj + (long)z * sAz;
  const unsigned short* Bb = B + (long)zi * sBi + (long)zj * sBj + (long)z * sBz;
  const long offC = (long)zi * sCi + (long)zj * sCj + (long)z * sCz;

  const int m0 = blockIdx.y * 128, n0 = blockIdx.x * 128;
  const int tid = threadIdx.x, wave = tid >> 6, lane = tid & 63;
  const int wm = (wave >> 1) * 64, wn = (wave & 1) * 64;
  const int srow = lane >> 2, scol = (lane & 3) * 8;
  const int l31 = lane & 31, khi = lane >> 5;

  f32x16 acc[2][2] = {};

  for (int k0 = 0; k0 < K; k0 += 64) {
#pragma unroll
    for (int h = 0; h < 2; ++h)
#pragma unroll
      for (int t = 0; t < 2; ++t) {
        const int r = wave * 32 + t * 16 + srow;
        gl_lds16(Ab + (long)(m0 + r) * lda + (k0 + h * 32 + scol), &lA[h][wave * 1024 + t * 512]);
        gl_lds16(Bb + (long)(n0 + r) * ldb + (k0 + h * 32 + scol), &lB[h][wave * 1024 + t * 512]);
      }
    __syncthreads();

    half8 af[2][4], bfr[2][4];
#pragma unroll
    for (int mi = 0; mi < 2; ++mi)
#pragma unroll
      for (int ks = 0; ks < 4; ++ks)
        af[mi][ks] = *(const half8*)&lA[ks >> 1][(wm + mi * 32 + l31) * 32 + (ks & 1) * 16 + khi * 8];
#pragma unroll
    for (int ni = 0; ni < 2; ++ni)
#pragma unroll
      for (int ks = 0; ks < 4; ++ks)
        bfr[ni][ks] = *(const half8*)&lB[ks >> 1][(wn + ni * 32 + l31) * 32 + (ks & 1) * 16 + khi * 8];

#pragma unroll
    for (int ks = 0; ks < 4; ++ks)
#pragma unroll
      for (int mi = 0; mi < 2; ++mi)
#pragma unroll
        for (int ni = 0; ni < 2; ++ni)
          acc[mi][ni] = __builtin_amdgcn_mfma_f32_32x32x16_f16(af[mi][ks], bfr[ni][ks], acc[mi][ni], 0, 0, 0);
    __syncthreads();
  }

  OutT* Cb = C + offC;
#pragma unroll
  for (int mi = 0; mi < 2; ++mi)
#pragma unroll
    for (int ni = 0; ni < 2; ++ni)
#pragma unroll
      for (int r = 0; r < 16; ++r) {
        const int row = m0 + wm + mi * 32 + khi * 4 + (r & 3) + 8 * (r >> 2);
        const int col = n0 + wn + ni * 32 + l31;
        float v = acc[mi][ni][r];
        if constexpr (EPI == 1) v = 1.0f - v;
        if constexpr (EPI == 2) v += e0[(long)row * 1024 + col];
        if constexpr (EPI == 3)
          v += e0[(long)gz * 1024 + row] * e2[col] + e1[(long)gz * 1024 + row] * e3[col];
        const long ci = (long)row * ldc + col;
        if constexpr (sizeof(OutT) == 2) {
          Cb[ci] = (OutT)f2h(v);
        } else {
          Cb[ci] = v;
        }
      }
}

// ctx = (w_pre * (1+dep[k])) @ Vb : near-pure GEMM, BK=64, mfma 32x32x16.
// A = w_pre fp16 [1024x1024] per gz, scaled by fp16 (1+dep[k]) via v_pk_mul during staging.
// B = Vt rows [zj*256 .. +256), k-cols [zi*1024 ..) via gl_lds16.
__global__ __launch_bounds__(256) void ctx_gemm(
    const unsigned short* __restrict__ wpre, const float* __restrict__ dep,
    const unsigned short* __restrict__ Vt, unsigned short* __restrict__ ctx)
{
  __shared__ __align__(16) unsigned short lA[2][4096];
  __shared__ __align__(16) unsigned short lB[2][4096];
  __shared__ __align__(16) unsigned short sDepH[1024];

  const int gz = blockIdx.z, zi = gz >> 2, zj = gz & 3;
  const int m0 = blockIdx.y * 128, n0 = blockIdx.x * 128;
  const int tid = threadIdx.x, wave = tid >> 6, lane = tid & 63;
  const int wm = (wave >> 1) * 64, wn = (wave & 1) * 64;
  const int srow = lane >> 2, scol = (lane & 3) * 8;
  const int l31 = lane & 31, khi = lane >> 5;

#pragma unroll
  for (int p = 0; p < 4; ++p)
    sDepH[tid + p * 256] = f2h(1.f + dep[(long)gz * 1024 + tid + p * 256]);
  __syncthreads();

  const unsigned short* Ab = wpre + (long)gz * TBB * TBB;
  const unsigned short* Bb = Vt + (long)(zj * 256) * TT + (long)zi * 1024;

  f32x16 acc[2][2] = {};

  for (int k0 = 0; k0 < 1024; k0 += 64) {
#pragma unroll
    for (int h = 0; h < 2; ++h)
#pragma unroll
      for (int t = 0; t < 2; ++t) {
        const int r = wave * 32 + t * 16 + srow;
        gl_lds16(Bb + (long)(n0 + r) * TT + (k0 + h * 32 + scol), &lB[h][wave * 1024 + t * 512]);
      }
#pragma unroll
    for (int h = 0; h < 2; ++h)
#pragma unroll
      for (int p = 0; p < 4; ++p) {
        const int idx = p * 1024 + tid * 4;
        const int row = idx >> 5, col = idx & 31;
        ushort4 wv = *(const ushort4*)(Ab + (long)(m0 + row) * 1024 + k0 + h * 32 + col);
        const half4 dv = *(const half4*)&sDepH[k0 + h * 32 + col];
        half4 pv = *(half4*)&wv * dv;
        *(half4*)&lA[h][row * 32 + col] = pv;
      }
    __syncthreads();

    half8 af[2][4], bfr[2][4];
#pragma unroll
    for (int mi = 0; mi < 2; ++mi)
#pragma unroll
      for (int ks = 0; ks < 4; ++ks)
        af[mi][ks] = *(const half8*)&lA[ks >> 1][(wm + mi * 32 + l31) * 32 + (ks & 1) * 16 + khi * 8];
#pragma unroll
    for (int ni = 0; ni < 2; ++ni)
#pragma unroll
      for (int ks = 0; ks < 4; ++ks)
        bfr[ni][ks] = *(const half8*)&lB[ks >> 1][(wn + ni * 32 + l31) * 32 + (ks & 1) * 16 + khi * 8];

#pragma unroll
    for (int ks = 0; ks < 4; ++ks)
#pragma unroll
      for (int mi = 0; mi < 2; ++mi)
#pragma unroll
        for (int ni = 0; ni < 2; ++ni)
          acc[mi][ni] = __builtin_amdgcn_mfma_f32_32x32x16_f16(af[mi][ks], bfr[ni][ks], acc[mi][ni], 0, 0, 0);
    __syncthreads();
  }

  unsigned short* Cb = ctx + (long)gz * TBB * WBB;
#pragma unroll
  for (int mi = 0; mi < 2; ++mi)
#pragma unroll
    for (int ni = 0; ni < 2; ++ni)
#pragma unroll
      for (int r = 0; r < 16; ++r) {
        const int row = m0 + wm + mi * 32 + khi * 4 + (r & 3) + 8 * (r >> 2);
        const int col = n0 + wn + ni * 32 + l31;
        Cb[(long)row * WBB + col] = f2h(acc[mi][ni][r]);
      }
}

__global__ __launch_bounds__(256) void prepx_kernel(
    const float* __restrict__ x, unsigned short* __restrict__ xh,
    unsigned short* __restrict__ xu)
{
  const int t = blockIdx.x, tid = threadIdx.x;
  const float4 v = *((const float4*)(x + (long)t * DD) + tid);
  float ss = v.x * v.x + v.y * v.y + v.z * v.z + v.w * v.w;
  ss = waveSum(ss);
  __shared__ float red[4];
  if ((tid & 63) == 0) red[tid >> 6] = ss;
  __syncthreads();
  const float tot = red[0] + red[1] + red[2] + red[3];
  const float inv = 1.f / fmaxf(sqrtf(tot), 1e-12f);
  ushort4 h, u;
  h.x = f2h(v.x); h.y = f2h(v.y); h.z = f2h(v.z); h.w = f2h(v.w);
  u.x = f2h(v.x * inv); u.y = f2h(v.y * inv); u.z = f2h(v.z * inv); u.w = f2h(v.w * inv);
  *((ushort4*)(xh + (long)t * DD) + tid) = h;
  *((ushort4*)(xu + (long)t * DD) + tid) = u;
}

__global__ __launch_bounds__(256) void castw_kernel(
    const float* __restrict__ Wq, const float* __restrict__ Wk, const float* __restrict__ Wv,
    unsigned short* __restrict__ o)
{
  const long idx4 = ((long)blockIdx.x * 256 + threadIdx.x) * 4;
  const int which = (int)(idx4 >> 20);
  const long loc = idx4 & ((1L << 20) - 1);
  const float* src = (which == 0) ? Wq : ((which == 1) ? Wk : Wv);
  const float4 v = *(const float4*)(src + loc);
  ushort4 h;
  h.x = f2h(v.x); h.y = f2h(v.y); h.z = f2h(v.z); h.w = f2h(v.w);
  *(ushort4*)(o + idx4) = h;
}

__global__ __launch_bounds__(256) void castp_kernel(const float* __restrict__ src,
                                                    unsigned short* __restrict__ dst)
{
  const long idx4 = ((long)blockIdx.x * 256 + threadIdx.x) * 4;
  const float4 v = *(const float4*)(src + idx4);
  ushort4 h;
  h.x = f2h(v.x); h.y = f2h(v.y); h.z = f2h(v.z); h.w = f2h(v.w);
  *(ushort4*)(dst + idx4) = h;
}

__global__ __launch_bounds__(256) void packw2_kernel(
    const float* __restrict__ W2, unsigned short* __restrict__ W2B,
    float* __restrict__ Ecol, float* __restrict__ Dcol)
{
  const int c = blockIdx.x, j = threadIdx.x;
  W2B[c * 256 + j] = f2h(W2[c * 258 + j]);
  if (j == 0) {
    Ecol[c] = W2[c * 258 + 256];
    Dcol[c] = W2[c * 258 + 257];
  }
}

__global__ __launch_bounds__(256) void ap_kernel(float* __restrict__ AP)
{
  const int p = blockIdx.x, tid = threadIdx.x;
#pragma unroll
  for (int t = 0; t < 4; ++t) {
    const int col = tid + t * 256;
    const int i = col >> 1;
    const float e = (2.0f * (float)i) / 1024.0f;
    const float ang = (float)p / powf(10000.0f, e);
    AP[(long)p * 1024 + col] = (col & 1) ? cosf(ang) : sinf(ang);
  }
}

__global__ __launch_bounds__(256) void transpose_kernel(
    const unsigned short* __restrict__ V, unsigned short* __restrict__ Vt)
{
  __shared__ unsigned short tile[32][33];
  const int tx = threadIdx.x & 31, ty = threadIdx.x >> 5;
  const int c0 = blockIdx.x * 32;
  const int r0 = blockIdx.y * 32;
#pragma unroll
  for (int rr = ty; rr < 32; rr += 8)
    tile[rr][tx] = V[(long)(r0 + rr) * DD + c0 + tx];
  __syncthreads();
#pragma unroll
  for (int rr = ty; rr < 32; rr += 8)
    Vt[(long)(c0 + rr) * TT + r0 + tx] = tile[tx][rr];
}

// Per (gz, q-row): softmax stats + dep + ent, writes w_pre = exp(s-m)/l as fp16.
__global__ __launch_bounds__(256) void stats_kernel(
    const float* __restrict__ sim, const unsigned short* __restrict__ divb,
    float* __restrict__ mrow, float* __restrict__ lrow,
    float* __restrict__ dep, float* __restrict__ ent,
    unsigned short* __restrict__ wpre)
{
  const int q = blockIdx.x, gz = blockIdx.y, bi = gz >> 2;
  const int tid = threadIdx.x;
  const float* srow = sim + ((long)gz * TBB + q) * TBB;
  const unsigned short* drow = divb + ((long)bi * TBB + q) * TBB;
  const float4 sv = ((const float4*)srow)[tid];
  const ushort4 dv = ((const ushort4*)drow)[tid];
  float s[4] = {sv.x, sv.y, sv.z, sv.w};
  float d[4] = {h2f(dv.x), h2f(dv.y), h2f(dv.z), h2f(dv.w)};
  float m = fmaxf(fmaxf(s[0], s[1]), fmaxf(s[2], s[3]));
  m = waveMax(m);
  __shared__ float red[4];
  if ((tid & 63) == 0) red[tid >> 6] = m;
  __syncthreads();
  m = fmaxf(fmaxf(red[0], red[1]), fmaxf(red[2], red[3]));
  float e[4];
  float l = 0.f, ss = 0.f, dn = 0.f, ds = 0.f;
#pragma unroll
  for (int p = 0; p < 4; ++p) {
    e[p] = expf(s[p] - m);
    l += e[p]; ss += e[p] * s[p]; dn += e[p] * d[p]; ds += d[p];
  }
  l = waveSum(l); ss = waveSum(ss); dn = waveSum(dn); ds = waveSum(ds);
  __shared__ float r2[16];
  if ((tid & 63) == 0) {
    const int w = tid >> 6;
    r2[w] = l; r2[4 + w] = ss; r2[8 + w] = dn; r2[12 + w] = ds;
  }
  __syncthreads();
  const float L = r2[0] + r2[1] + r2[2] + r2[3];
  const float Li = 1.f / L;
  ushort4 wq;
  wq.x = f2h(e[0] * Li); wq.y = f2h(e[1] * Li);
  wq.z = f2h(e[2] * Li); wq.w = f2h(e[3] * Li);
  ((ushort4*)(wpre + ((long)gz * TBB + q) * TBB))[tid] = wq;
  if (tid == 0) {
    const float SS = r2[4] + r2[5] + r2[6] + r2[7];
    const float DN = r2[8] + r2[9] + r2[10] + r2[11];
    const float DS = r2[12] + r2[13] + r2[14] + r2[15];
    const long o = (long)gz * TBB + q;
    mrow[o] = m;
    lrow[o] = L;
    dep[o] = (DN * Li) / DS;
    ent[o] = (m + logf(L) - SS * Li) * 0.14426950408889634f;  // 1/ln(1024)
  }
}

__global__ __launch_bounds__(256) void entnorm_kernel(float* __restrict__ ent)
{
  const int gz = blockIdx.x, tid = threadIdx.x;
  float s = 0.f;
#pragma unroll
  for (int p = 0; p < 4; ++p) s += fabsf(ent[(long)gz * TBB + tid + p * 256]);
  s = waveSum(s);
  __shared__ float red[4];
  if ((tid & 63) == 0) red[tid >> 6] = s;
  __syncthreads();
  const float scale = 1.f / fmaxf(red[0] + red[1] + red[2] + red[3], 1e-12f);
#pragma unroll
  for (int p = 0; p < 4; ++p) ent[(long)gz * TBB + tid + p * 256] *= scale;
}

extern "C" void kernel_launch(void* const* d_in, const int* in_sizes, int n_in,
                              void* d_out, int out_size, void* d_ws, size_t ws_size,
                              hipStream_t stream)
{
  const float* x  = (const float*)d_in[0];
  const float* Wq = (const float*)d_in[1];
  const float* Wk = (const float*)d_in[2];
  const float* Wv = (const float*)d_in[3];
  const float* Wo = (const float*)d_in[4];
  const float* W2 = (const float*)d_in[5];

  char* ws = (char*)d_ws;
  size_t off = 0;
  auto take = [&](size_t bytes) -> void* {
    void* p = ws + off;
    off += (bytes + 255) & ~(size_t)255;
    return p;
  };
  unsigned short* QKV = (unsigned short*)take((size_t)3 * TT * DD * 2);
  unsigned short* xh  = (unsigned short*)take((size_t)TT * DD * 2);
  unsigned short* xu  = (unsigned short*)take((size_t)TT * DD * 2);
  unsigned short* Wh  = (unsigned short*)take((size_t)3 * DD * DD * 2);
  unsigned short* WoB = (unsigned short*)take((size_t)DD * DD * 2);
  unsigned short* W2B = (unsigned short*)take((size_t)256 * 256 * 2);
  float* Ecol = (float*)take(256 * 4);
  float* Dcol = (float*)take(256 * 4);
  float* AP   = (float*)take((size_t)TBB * TBB * 4);
  unsigned short* divb = (unsigned short*)take((size_t)4 * TBB * TBB * 2);
  unsigned short* Vt = (unsigned short*)take((size_t)DD * TT * 2);
  float* simb = (float*)take((size_t)16 * TBB * TBB * 4);
  unsigned short* wpre = (unsigned short*)take((size_t)16 * TBB * TBB * 2);
  float* mrow = (float*)take((size_t)16 * TBB * 4);
  float* lrow = (float*)take((size_t)16 * TBB * 4);
  float* depb = (float*)take((size_t)16 * TBB * 4);
  float* entb = (float*)take((size_t)16 * TBB * 4);
  unsigned short* ctx = (unsigned short*)take((size_t)16 * TBB * WBB * 2);
  unsigned short* Y = (unsigned short*)take((size_t)TT * DD * 2);
  (void)ws_size; (void)in_sizes; (void)n_in; (void)out_size;

  prepx_kernel<<<TT, 256, 0, stream>>>(x, xh, xu);
  castw_kernel<<<(3 * DD * DD) / 1024, 256, 0, stream>>>(Wq, Wk, Wv, Wh);
  castp_kernel<<<(DD * DD) / 1024, 256, 0, stream>>>(Wo, WoB);
  packw2_kernel<<<256, 256, 0, stream>>>(W2, W2B, Ecol, Dcol);
  ap_kernel<<<TBB, 256, 0, stream>>>(AP);

  // QKV projection: Q|K|V [4096,1024] each, fp16
  gemm_bt<0, unsigned short><<<dim3(DD / 128, TT / 128, 3), 256, 0, stream>>>(
      xh, Wh, QKV,
      DD, DD, DD, DD, 0, 1,
      0, 0, (long)DD * DD, 0, (long)TT * DD, 0,
      0, 0, 0, nullptr, nullptr, nullptr, nullptr);

  transpose_kernel<<<dim3(DD / 32, TT / 32), 256, 0, stream>>>(QKV + (size_t)2 * TT * DD, Vt);

  // div diagonal blocks: 1 - xu_i @ xu_i^T, fp16 out
  gemm_bt<1, unsigned short><<<dim3(8, 8, 4), 256, 0, stream>>>(
      xu, xu, divb,
      DD, DD, DD, TBB, 0, 1,
      (long)TBB * DD, 0, (long)TBB * DD, 0, (long)TBB * TBB, 0,
      0, 0, 0, nullptr, nullptr, nullptr, nullptr);

  const unsigned short* Qh = QKV;
  const unsigned short* Kh = QKV + (size_t)TT * DD;

  // sim = Qb @ Kb^T + AP, all 16 blocks
  gemm_bt<2, float><<<dim3(8, 8, 16), 256, 0, stream>>>(
      Qh, Kh, simb,
      WBB, DD, DD, TBB, 0, 4,
      (long)TBB * DD, WBB, (long)TBB * DD, WBB, 0, 0,
      0, 0, (long)TBB * TBB, AP, nullptr, nullptr, nullptr);

  stats_kernel<<<dim3(TBB, 16), 256, 0, stream>>>(simb, divb, mrow, lrow, depb, entb, wpre);
  entnorm_kernel<<<16, 256, 0, stream>>>(entb);

  // ctx = (w_pre * (1+dep[k])) @ Vb
  ctx_gemm<<<dim3(2, 8, 16), 256, 0, stream>>>(wpre, depb, Vt, ctx);

  // y = [ctx | ent | dep] @ Wout2^T, scattered back to [4096,1024]
  gemm_bt<3, unsigned short><<<dim3(2, 8, 16), 256, 0, stream>>>(
      ctx, W2B, Y,
      WBB, WBB, WBB, DD, 0, 4,
      (long)4 * TBB * WBB, (long)TBB * WBB, 0, 0, (long)TBB * DD, (long)WBB,
      0, 0, 0, entb, depb, Ecol, Dcol);

  // out = Y @ Wout^T
  gemm_bt<0, float><<<dim3(8, 32, 1), 256, 0, stream>>>(
      Y, WoB, (float*)d_out,
      DD, DD, DD, DD, 0, 1,
      0, 0, 0, 0, 0, 0,
      0, 0, 0, nullptr, nullptr, nullptr, nullptr);
}

// Round 5
// 277.242 us; speedup vs baseline: 1.7905x; 1.0553x over previous
//
#include <hip/hip_runtime.h>
#include <hip/hip_bf16.h>

#define TT 4096
#define DD 1024
#define TBB 1024
#define WBB 256

typedef __attribute__((ext_vector_type(8))) _Float16 half8;
typedef __attribute__((ext_vector_type(4))) _Float16 half4;
typedef __attribute__((ext_vector_type(4))) float f32x4;
typedef __attribute__((ext_vector_type(16))) float f32x16;

__device__ __forceinline__ unsigned short f2h(float v) {
  _Float16 h = (_Float16)v;
  return *reinterpret_cast<unsigned short*>(&h);
}
__device__ __forceinline__ float h2f(unsigned short u) {
  _Float16 h = *reinterpret_cast<_Float16*>(&u);
  return (float)h;
}

__device__ __forceinline__ void gl_lds16(const unsigned short* g, unsigned short* l) {
  __builtin_amdgcn_global_load_lds(
      (const __attribute__((address_space(1))) void*)(unsigned long long)(g),
      (__attribute__((address_space(3))) void*)(unsigned long long)(l),
      16, 0, 0);
}

__device__ __forceinline__ float waveSum(float v) {
#pragma unroll
  for (int o = 32; o > 0; o >>= 1) v += __shfl_down(v, o, 64);
  return v;
}
__device__ __forceinline__ float waveMax(float v) {
#pragma unroll
  for (int o = 32; o > 0; o >>= 1) v = fmaxf(v, __shfl_down(v, o, 64));
  return v;
}

// Generic C = A (MxK) * B^T (B is NxK), fp16, 128x128 tile, 4 waves,
// BK=64, mfma 32x32x16 f16, XOR bank swizzle: chunk p = c ^ ((row>>1)&3).
// EPI: 0 plain, 1 -> 1-acc, 2 -> +e0[row*1024+col] (abs-pos), 3 -> +ent/dep cols
template <int EPI, typename OutT>
__global__ __launch_bounds__(256) void gemm_bt(
    const unsigned short* __restrict__ A, const unsigned short* __restrict__ B,
    OutT* __restrict__ C,
    int K, int lda, int ldb, int ldc,
    int zbase, int zdiv,
    long sAi, long sAj, long sBi, long sBj, long sCi, long sCj,
    long sAz, long sBz, long sCz,
    const float* __restrict__ e0, const float* __restrict__ e1,
    const float* __restrict__ e2, const float* __restrict__ e3)
{
  __shared__ __align__(16) unsigned short lA[2][4096];
  __shared__ __align__(16) unsigned short lB[2][4096];

  const int z = blockIdx.z, gz = zbase + z;
  const int zi = gz / zdiv, zj = gz - zi * zdiv;
  const unsigned short* Ab = A + (long)zi * sAi + (long)zj * sAj + (long)z * sAz;
  const unsigned short* Bb = B + (long)zi * sBi + (long)zj * sBj + (long)z * sBz;
  const long offC = (long)zi * sCi + (long)zj * sCj + (long)z * sCz;

  const int m0 = blockIdx.y * 128, n0 = blockIdx.x * 128;
  const int tid = threadIdx.x, wave = tid >> 6, lane = tid & 63;
  const int wm = (wave >> 1) * 64, wn = (wave & 1) * 64;
  const int srow = lane >> 2;
  // swizzled source column chunk: data lands pre-swizzled in LDS
  const int scol = (((lane & 3) ^ ((srow >> 1) & 3))) * 8;
  const int l31 = lane & 31, khi = lane >> 5;
  const int sw2 = (l31 >> 1) & 3;

  f32x16 acc[2][2] = {};

  for (int k0 = 0; k0 < K; k0 += 64) {
#pragma unroll
    for (int h = 0; h < 2; ++h)
#pragma unroll
      for (int t = 0; t < 2; ++t) {
        const int r = wave * 32 + t * 16 + srow;
        gl_lds16(Ab + (long)(m0 + r) * lda + (k0 + h * 32 + scol), &lA[h][wave * 1024 + t * 512]);
        gl_lds16(Bb + (long)(n0 + r) * ldb + (k0 + h * 32 + scol), &lB[h][wave * 1024 + t * 512]);
      }
    __syncthreads();

    half8 af[2][4], bfr[2][4];
#pragma unroll
    for (int mi = 0; mi < 2; ++mi)
#pragma unroll
      for (int ks = 0; ks < 4; ++ks)
        af[mi][ks] = *(const half8*)&lA[ks >> 1][(wm + mi * 32 + l31) * 32 + ((((ks & 1) * 2 + khi) ^ sw2) * 8)];
#pragma unroll
    for (int ni = 0; ni < 2; ++ni)
#pragma unroll
      for (int ks = 0; ks < 4; ++ks)
        bfr[ni][ks] = *(const half8*)&lB[ks >> 1][(wn + ni * 32 + l31) * 32 + ((((ks & 1) * 2 + khi) ^ sw2) * 8)];

#pragma unroll
    for (int ks = 0; ks < 4; ++ks)
#pragma unroll
      for (int mi = 0; mi < 2; ++mi)
#pragma unroll
        for (int ni = 0; ni < 2; ++ni)
          acc[mi][ni] = __builtin_amdgcn_mfma_f32_32x32x16_f16(af[mi][ks], bfr[ni][ks], acc[mi][ni], 0, 0, 0);
    __syncthreads();
  }

  OutT* Cb = C + offC;
#pragma unroll
  for (int mi = 0; mi < 2; ++mi)
#pragma unroll
    for (int ni = 0; ni < 2; ++ni)
#pragma unroll
      for (int r = 0; r < 16; ++r) {
        const int row = m0 + wm + mi * 32 + khi * 4 + (r & 3) + 8 * (r >> 2);
        const int col = n0 + wn + ni * 32 + l31;
        float v = acc[mi][ni][r];
        if constexpr (EPI == 1) v = 1.0f - v;
        if constexpr (EPI == 2) v += e0[(long)row * 1024 + col];
        if constexpr (EPI == 3)
          v += e0[(long)gz * 1024 + row] * e2[col] + e1[(long)gz * 1024 + row] * e3[col];
        const long ci = (long)row * ldc + col;
        if constexpr (sizeof(OutT) == 2) {
          Cb[ci] = (OutT)f2h(v);
        } else {
          Cb[ci] = v;
        }
      }
}

// ctx = (w_pre * (1+dep[k])) @ Vb : near-pure GEMM, BK=64, mfma 32x32x16, swizzled LDS.
__global__ __launch_bounds__(256) void ctx_gemm(
    const unsigned short* __restrict__ wpre, const float* __restrict__ dep,
    const unsigned short* __restrict__ Vt, unsigned short* __restrict__ ctx)
{
  __shared__ __align__(16) unsigned short lA[2][4096];
  __shared__ __align__(16) unsigned short lB[2][4096];
  __shared__ __align__(16) unsigned short sDepH[1024];

  const int gz = blockIdx.z, zi = gz >> 2, zj = gz & 3;
  const int m0 = blockIdx.y * 128, n0 = blockIdx.x * 128;
  const int tid = threadIdx.x, wave = tid >> 6, lane = tid & 63;
  const int wm = (wave >> 1) * 64, wn = (wave & 1) * 64;
  const int srow = lane >> 2;
  const int scol = (((lane & 3) ^ ((srow >> 1) & 3))) * 8;
  const int l31 = lane & 31, khi = lane >> 5;
  const int sw2 = (l31 >> 1) & 3;

#pragma unroll
  for (int p = 0; p < 4; ++p)
    sDepH[tid + p * 256] = f2h(1.f + dep[(long)gz * 1024 + tid + p * 256]);
  __syncthreads();

  const unsigned short* Ab = wpre + (long)gz * TBB * TBB;
  const unsigned short* Bb = Vt + (long)(zj * 256) * TT + (long)zi * 1024;

  f32x16 acc[2][2] = {};

  for (int k0 = 0; k0 < 1024; k0 += 64) {
#pragma unroll
    for (int h = 0; h < 2; ++h)
#pragma unroll
      for (int t = 0; t < 2; ++t) {
        const int r = wave * 32 + t * 16 + srow;
        gl_lds16(Bb + (long)(n0 + r) * TT + (k0 + h * 32 + scol), &lB[h][wave * 1024 + t * 512]);
      }
#pragma unroll
    for (int h = 0; h < 2; ++h)
#pragma unroll
      for (int p = 0; p < 4; ++p) {
        const int idx = p * 1024 + tid * 4;
        const int row = idx >> 5, col = idx & 31;
        ushort4 wv = *(const ushort4*)(Ab + (long)(m0 + row) * 1024 + k0 + h * 32 + col);
        const half4 dv = *(const half4*)&sDepH[k0 + h * 32 + col];
        half4 pv = *(half4*)&wv * dv;
        const int pcol = (((col >> 3) ^ ((row >> 1) & 3)) << 3) | (col & 7);
        *(half4*)&lA[h][row * 32 + pcol] = pv;
      }
    __syncthreads();

    half8 af[2][4], bfr[2][4];
#pragma unroll
    for (int mi = 0; mi < 2; ++mi)
#pragma unroll
      for (int ks = 0; ks < 4; ++ks)
        af[mi][ks] = *(const half8*)&lA[ks >> 1][(wm + mi * 32 + l31) * 32 + ((((ks & 1) * 2 + khi) ^ sw2) * 8)];
#pragma unroll
    for (int ni = 0; ni < 2; ++ni)
#pragma unroll
      for (int ks = 0; ks < 4; ++ks)
        bfr[ni][ks] = *(const half8*)&lB[ks >> 1][(wn + ni * 32 + l31) * 32 + ((((ks & 1) * 2 + khi) ^ sw2) * 8)];

#pragma unroll
    for (int ks = 0; ks < 4; ++ks)
#pragma unroll
      for (int mi = 0; mi < 2; ++mi)
#pragma unroll
        for (int ni = 0; ni < 2; ++ni)
          acc[mi][ni] = __builtin_amdgcn_mfma_f32_32x32x16_f16(af[mi][ks], bfr[ni][ks], acc[mi][ni], 0, 0, 0);
    __syncthreads();
  }

  unsigned short* Cb = ctx + (long)gz * TBB * WBB;
#pragma unroll
  for (int mi = 0; mi < 2; ++mi)
#pragma unroll
    for (int ni = 0; ni < 2; ++ni)
#pragma unroll
      for (int r = 0; r < 16; ++r) {
        const int row = m0 + wm + mi * 32 + khi * 4 + (r & 3) + 8 * (r >> 2);
        const int col = n0 + wn + ni * 32 + l31;
        Cb[(long)row * WBB + col] = f2h(acc[mi][ni][r]);
      }
}

__global__ __launch_bounds__(256) void prepx_kernel(
    const float* __restrict__ x, unsigned short* __restrict__ xh,
    unsigned short* __restrict__ xu)
{
  const int t = blockIdx.x, tid = threadIdx.x;
  const float4 v = *((const float4*)(x + (long)t * DD) + tid);
  float ss = v.x * v.x + v.y * v.y + v.z * v.z + v.w * v.w;
  ss = waveSum(ss);
  __shared__ float red[4];
  if ((tid & 63) == 0) red[tid >> 6] = ss;
  __syncthreads();
  const float tot = red[0] + red[1] + red[2] + red[3];
  const float inv = 1.f / fmaxf(sqrtf(tot), 1e-12f);
  ushort4 h, u;
  h.x = f2h(v.x); h.y = f2h(v.y); h.z = f2h(v.z); h.w = f2h(v.w);
  u.x = f2h(v.x * inv); u.y = f2h(v.y * inv); u.z = f2h(v.z * inv); u.w = f2h(v.w * inv);
  *((ushort4*)(xh + (long)t * DD) + tid) = h;
  *((ushort4*)(xu + (long)t * DD) + tid) = u;
}

__global__ __launch_bounds__(256) void castw_kernel(
    const float* __restrict__ Wq, const float* __restrict__ Wk, const float* __restrict__ Wv,
    unsigned short* __restrict__ o)
{
  const long idx4 = ((long)blockIdx.x * 256 + threadIdx.x) * 4;
  const int which = (int)(idx4 >> 20);
  const long loc = idx4 & ((1L << 20) - 1);
  const float* src = (which == 0) ? Wq : ((which == 1) ? Wk : Wv);
  const float4 v = *(const float4*)(src + loc);
  ushort4 h;
  h.x = f2h(v.x); h.y = f2h(v.y); h.z = f2h(v.z); h.w = f2h(v.w);
  *(ushort4*)(o + idx4) = h;
}

__global__ __launch_bounds__(256) void castp_kernel(const float* __restrict__ src,
                                                    unsigned short* __restrict__ dst)
{
  const long idx4 = ((long)blockIdx.x * 256 + threadIdx.x) * 4;
  const float4 v = *(const float4*)(src + idx4);
  ushort4 h;
  h.x = f2h(v.x); h.y = f2h(v.y); h.z = f2h(v.z); h.w = f2h(v.w);
  *(ushort4*)(dst + idx4) = h;
}

__global__ __launch_bounds__(256) void packw2_kernel(
    const float* __restrict__ W2, unsigned short* __restrict__ W2B,
    float* __restrict__ Ecol, float* __restrict__ Dcol)
{
  const int c = blockIdx.x, j = threadIdx.x;
  W2B[c * 256 + j] = f2h(W2[c * 258 + j]);
  if (j == 0) {
    Ecol[c] = W2[c * 258 + 256];
    Dcol[c] = W2[c * 258 + 257];
  }
}

__global__ __launch_bounds__(256) void ap_kernel(float* __restrict__ AP)
{
  const int p = blockIdx.x, tid = threadIdx.x;
#pragma unroll
  for (int t = 0; t < 4; ++t) {
    const int col = tid + t * 256;
    const int i = col >> 1;
    const float e = (2.0f * (float)i) / 1024.0f;
    const float ang = (float)p / powf(10000.0f, e);
    AP[(long)p * 1024 + col] = (col & 1) ? cosf(ang) : sinf(ang);
  }
}

__global__ __launch_bounds__(256) void transpose_kernel(
    const unsigned short* __restrict__ V, unsigned short* __restrict__ Vt)
{
  __shared__ unsigned short tile[32][33];
  const int tx = threadIdx.x & 31, ty = threadIdx.x >> 5;
  const int c0 = blockIdx.x * 32;
  const int r0 = blockIdx.y * 32;
#pragma unroll
  for (int rr = ty; rr < 32; rr += 8)
    tile[rr][tx] = V[(long)(r0 + rr) * DD + c0 + tx];
  __syncthreads();
#pragma unroll
  for (int rr = ty; rr < 32; rr += 8)
    Vt[(long)(c0 + rr) * TT + r0 + tx] = tile[tx][rr];
}

// Per (gz, q-row): softmax stats + dep + ent, writes w_pre = exp(s-m)/l as fp16.
__global__ __launch_bounds__(256) void stats_kernel(
    const float* __restrict__ sim, const unsigned short* __restrict__ divb,
    float* __restrict__ mrow, float* __restrict__ lrow,
    float* __restrict__ dep, float* __restrict__ ent,
    unsigned short* __restrict__ wpre)
{
  const int q = blockIdx.x, gz = blockIdx.y, bi = gz >> 2;
  const int tid = threadIdx.x;
  const float* srow = sim + ((long)gz * TBB + q) * TBB;
  const unsigned short* drow = divb + ((long)bi * TBB + q) * TBB;
  const float4 sv = ((const float4*)srow)[tid];
  const ushort4 dv = ((const ushort4*)drow)[tid];
  float s[4] = {sv.x, sv.y, sv.z, sv.w};
  float d[4] = {h2f(dv.x), h2f(dv.y), h2f(dv.z), h2f(dv.w)};
  float m = fmaxf(fmaxf(s[0], s[1]), fmaxf(s[2], s[3]));
  m = waveMax(m);
  __shared__ float red[4];
  if ((tid & 63) == 0) red[tid >> 6] = m;
  __syncthreads();
  m = fmaxf(fmaxf(red[0], red[1]), fmaxf(red[2], red[3]));
  float e[4];
  float l = 0.f, ss = 0.f, dn = 0.f, ds = 0.f;
#pragma unroll
  for (int p = 0; p < 4; ++p) {
    e[p] = expf(s[p] - m);
    l += e[p]; ss += e[p] * s[p]; dn += e[p] * d[p]; ds += d[p];
  }
  l = waveSum(l); ss = waveSum(ss); dn = waveSum(dn); ds = waveSum(ds);
  __shared__ float r2[16];
  if ((tid & 63) == 0) {
    const int w = tid >> 6;
    r2[w] = l; r2[4 + w] = ss; r2[8 + w] = dn; r2[12 + w] = ds;
  }
  __syncthreads();
  const float L = r2[0] + r2[1] + r2[2] + r2[3];
  const float Li = 1.f / L;
  ushort4 wq;
  wq.x = f2h(e[0] * Li); wq.y = f2h(e[1] * Li);
  wq.z = f2h(e[2] * Li); wq.w = f2h(e[3] * Li);
  ((ushort4*)(wpre + ((long)gz * TBB + q) * TBB))[tid] = wq;
  if (tid == 0) {
    const float SS = r2[4] + r2[5] + r2[6] + r2[7];
    const float DN = r2[8] + r2[9] + r2[10] + r2[11];
    const float DS = r2[12] + r2[13] + r2[14] + r2[15];
    const long o = (long)gz * TBB + q;
    mrow[o] = m;
    lrow[o] = L;
    dep[o] = (DN * Li) / DS;
    ent[o] = (m + logf(L) - SS * Li) * 0.14426950408889634f;  // 1/ln(1024)
  }
}

__global__ __launch_bounds__(256) void entnorm_kernel(float* __restrict__ ent)
{
  const int gz = blockIdx.x, tid = threadIdx.x;
  float s = 0.f;
#pragma unroll
  for (int p = 0; p < 4; ++p) s += fabsf(ent[(long)gz * TBB + tid + p * 256]);
  s = waveSum(s);
  __shared__ float red[4];
  if ((tid & 63) == 0) red[tid >> 6] = s;
  __syncthreads();
  const float scale = 1.f / fmaxf(red[0] + red[1] + red[2] + red[3], 1e-12f);
#pragma unroll
  for (int p = 0; p < 4; ++p) ent[(long)gz * TBB + tid + p * 256] *= scale;
}

extern "C" void kernel_launch(void* const* d_in, const int* in_sizes, int n_in,
                              void* d_out, int out_size, void* d_ws, size_t ws_size,
                              hipStream_t stream)
{
  const float* x  = (const float*)d_in[0];
  const float* Wq = (const float*)d_in[1];
  const float* Wk = (const float*)d_in[2];
  const float* Wv = (const float*)d_in[3];
  const float* Wo = (const float*)d_in[4];
  const float* W2 = (const float*)d_in[5];

  char* ws = (char*)d_ws;
  size_t off = 0;
  auto take = [&](size_t bytes) -> void* {
    void* p = ws + off;
    off += (bytes + 255) & ~(size_t)255;
    return p;
  };
  unsigned short* QKV = (unsigned short*)take((size_t)3 * TT * DD * 2);
  unsigned short* xh  = (unsigned short*)take((size_t)TT * DD * 2);
  unsigned short* xu  = (unsigned short*)take((size_t)TT * DD * 2);
  unsigned short* Wh  = (unsigned short*)take((size_t)3 * DD * DD * 2);
  unsigned short* WoB = (unsigned short*)take((size_t)DD * DD * 2);
  unsigned short* W2B = (unsigned short*)take((size_t)256 * 256 * 2);
  float* Ecol = (float*)take(256 * 4);
  float* Dcol = (float*)take(256 * 4);
  float* AP   = (float*)take((size_t)TBB * TBB * 4);
  unsigned short* divb = (unsigned short*)take((size_t)4 * TBB * TBB * 2);
  unsigned short* Vt = (unsigned short*)take((size_t)DD * TT * 2);
  float* simb = (float*)take((size_t)16 * TBB * TBB * 4);
  unsigned short* wpre = (unsigned short*)take((size_t)16 * TBB * TBB * 2);
  float* mrow = (float*)take((size_t)16 * TBB * 4);
  float* lrow = (float*)take((size_t)16 * TBB * 4);
  float* depb = (float*)take((size_t)16 * TBB * 4);
  float* entb = (float*)take((size_t)16 * TBB * 4);
  unsigned short* ctx = (unsigned short*)take((size_t)16 * TBB * WBB * 2);
  unsigned short* Y = (unsigned short*)take((size_t)TT * DD * 2);
  (void)ws_size; (void)in_sizes; (void)n_in; (void)out_size;

  prepx_kernel<<<TT, 256, 0, stream>>>(x, xh, xu);
  castw_kernel<<<(3 * DD * DD) / 1024, 256, 0, stream>>>(Wq, Wk, Wv, Wh);
  castp_kernel<<<(DD * DD) / 1024, 256, 0, stream>>>(Wo, WoB);
  packw2_kernel<<<256, 256, 0, stream>>>(W2, W2B, Ecol, Dcol);
  ap_kernel<<<TBB, 256, 0, stream>>>(AP);

  // QKV projection: Q|K|V [4096,1024] each, fp16
  gemm_bt<0, unsigned short><<<dim3(DD / 128, TT / 128, 3), 256, 0, stream>>>(
      xh, Wh, QKV,
      DD, DD, DD, DD, 0, 1,
      0, 0, (long)DD * DD, 0, (long)TT * DD, 0,
      0, 0, 0, nullptr, nullptr, nullptr, nullptr);

  transpose_kernel<<<dim3(DD / 32, TT / 32), 256, 0, stream>>>(QKV + (size_t)2 * TT * DD, Vt);

  // div diagonal blocks: 1 - xu_i @ xu_i^T, fp16 out
  gemm_bt<1, unsigned short><<<dim3(8, 8, 4), 256, 0, stream>>>(
      xu, xu, divb,
      DD, DD, DD, TBB, 0, 1,
      (long)TBB * DD, 0, (long)TBB * DD, 0, (long)TBB * TBB, 0,
      0, 0, 0, nullptr, nullptr, nullptr, nullptr);

  const unsigned short* Qh = QKV;
  const unsigned short* Kh = QKV + (size_t)TT * DD;

  // sim = Qb @ Kb^T + AP, all 16 blocks
  gemm_bt<2, float><<<dim3(8, 8, 16), 256, 0, stream>>>(
      Qh, Kh, simb,
      WBB, DD, DD, TBB, 0, 4,
      (long)TBB * DD, WBB, (long)TBB * DD, WBB, 0, 0,
      0, 0, (long)TBB * TBB, AP, nullptr, nullptr, nullptr);

  stats_kernel<<<dim3(TBB, 16), 256, 0, stream>>>(simb, divb, mrow, lrow, depb, entb, wpre);
  entnorm_kernel<<<16, 256, 0, stream>>>(entb);

  // ctx = (w_pre * (1+dep[k])) @ Vb
  ctx_gemm<<<dim3(2, 8, 16), 256, 0, stream>>>(wpre, depb, Vt, ctx);

  // y = [ctx | ent | dep] @ Wout2^T, scattered back to [4096,1024]
  gemm_bt<3, unsigned short><<<dim3(2, 8, 16), 256, 0, stream>>>(
      ctx, W2B, Y,
      WBB, WBB, WBB, DD, 0, 4,
      (long)4 * TBB * WBB, (long)TBB * WBB, 0, 0, (long)TBB * DD, (long)WBB,
      0, 0, 0, entb, depb, Ecol, Dcol);

  // out = Y @ Wout^T
  gemm_bt<0, float><<<dim3(8, 32, 1), 256, 0, stream>>>(
      Y, WoB, (float*)d_out,
      DD, DD, DD, DD, 0, 1,
      0, 0, 0, 0, 0, 0,
      0, 0, 0, nullptr, nullptr, nullptr, nullptr);
}